// Round 20
// baseline (437.322 us; speedup 1.0000x reference)
//
#include <hip/hip_runtime.h>

typedef unsigned short u16;
typedef unsigned short u16x8 __attribute__((ext_vector_type(8)));
typedef short s16x8 __attribute__((ext_vector_type(8)));
typedef float f32x4 __attribute__((ext_vector_type(4)));

#define EL ((size_t)3145728)       // 4096*768
#define DDE ((size_t)589824)       // 768*768
#define DFE ((size_t)2359296)      // 768*3072

#if __has_builtin(__builtin_amdgcn_exp2f)
#define EXP2(x) __builtin_amdgcn_exp2f(x)
#else
#define EXP2(x) __expf((x) * 0.6931471805599453f)
#endif

__device__ __forceinline__ float b2f(u16 u) {
    return __builtin_bit_cast(float, (unsigned)u << 16);
}
__device__ __forceinline__ u16 f2bf(float f) {
    unsigned x = __builtin_bit_cast(unsigned, f);
    return (u16)((x + 0x7fffu + ((x >> 16) & 1u)) >> 16);
}
__device__ __forceinline__ float gelu_f(float x) {
    float t = x + 0.044715f * x * x * x;
    return x * __builtin_amdgcn_rcpf(1.0f + EXP2(-2.302207417f * t));
}
__device__ __forceinline__ f32x4 mfma16(s16x8 a, s16x8 b, f32x4 c) {
    return __builtin_amdgcn_mfma_f32_16x16x32_bf16(a, b, c, 0, 0, 0);
}
__device__ __forceinline__ void gld16(const u16* g, u16* l) {
    __builtin_amdgcn_global_load_lds((const __attribute__((address_space(1))) void*)g,
                                     (__attribute__((address_space(3))) void*)l,
                                     16, 0, 0);
}
// XCD panel-ownership map: 1D grid T (T%8==0, (T/8)%NN==0).
__device__ __forceinline__ void xcd_map(int NN, int& m, int& n, int& z, int& ks) {
    int p = blockIdx.x, T = gridDim.x;
    int ppx = T >> 3;
    int xcd = p & 7, l = p >> 3;
    int panel = l / NN;
    n = l - panel * NN;
    int gp = xcd * (ppx / NN) + panel;
    m = gp & 31;
    z = (gp >> 5) & 1;
    ks = gp >> 6;
}

// ------- transpose+cast, 8-batch (768x768 each): z selects src; dst+z*DDE ----
__global__ __launch_bounds__(256) void transpose8_k(const float* p0, const float* p1,
                                                    const float* p2, const float* p3,
                                                    const float* p4, const float* p5,
                                                    const float* p6, const float* p7,
                                                    u16* __restrict__ dst0) {
    int z = blockIdx.z;
    const float* in = z == 0 ? p0 : z == 1 ? p1 : z == 2 ? p2 : z == 3 ? p3
                    : z == 4 ? p4 : z == 5 ? p5 : z == 6 ? p6 : p7;
    u16* out = dst0 + (size_t)z * DDE;
    const int K = 768, N = 768;
    __shared__ u16 tile[64][72];
    int k0 = blockIdx.y << 6, n0 = blockIdx.x << 6;
    int tid = threadIdx.x;
    int r = tid >> 2, c = (tid & 3) << 4;
    const float* ip = in + (size_t)(k0 + r) * N + n0 + c;
#pragma unroll
    for (int q = 0; q < 4; ++q) {
        f32x4 v = *(const f32x4*)(ip + 4 * q);
#pragma unroll
        for (int e = 0; e < 4; ++e) tile[r][c + 4 * q + e] = f2bf(v[e]);
    }
    __syncthreads();
    u16x8 o0, o1;
#pragma unroll
    for (int e = 0; e < 8; ++e) { o0[e] = tile[c + e][r]; o1[e] = tile[c + 8 + e][r]; }
    u16* op = out + (size_t)(n0 + r) * K + k0 + c;
    *(u16x8*)op = o0;
    *(u16x8*)(op + 8) = o1;
}

// ------- transpose+cast, 2-batch: in [K][N] f32 -> out bf16 [N][K] -----------
__global__ __launch_bounds__(256) void transpose2_k(const float* pa, const float* pb,
                                                    u16* __restrict__ dst0, size_t dsz,
                                                    int K, int N) {
    int z = blockIdx.z;
    const float* in = z ? pb : pa;
    u16* out = dst0 + (size_t)z * dsz;
    __shared__ u16 tile[64][72];
    int k0 = blockIdx.y << 6, n0 = blockIdx.x << 6;
    int tid = threadIdx.x;
    int r = tid >> 2, c = (tid & 3) << 4;
    const float* ip = in + (size_t)(k0 + r) * N + n0 + c;
#pragma unroll
    for (int q = 0; q < 4; ++q) {
        f32x4 v = *(const f32x4*)(ip + 4 * q);
#pragma unroll
        for (int e = 0; e < 4; ++e) tile[r][c + 4 * q + e] = f2bf(v[e]);
    }
    __syncthreads();
    u16x8 o0, o1;
#pragma unroll
    for (int e = 0; e < 8; ++e) { o0[e] = tile[c + e][r]; o1[e] = tile[c + 8 + e][r]; }
    u16* op = out + (size_t)(n0 + r) * K + k0 + c;
    *(u16x8*)op = o0;
    *(u16x8*)(op + 8) = o1;
}

// ------- V row-major [B,H,S,64] -> VT [B,H,64,S]; grid (16 st, 48 bh, 2 z) ---
__global__ __launch_bounds__(256) void vtrans_k(const u16* __restrict__ Vrow,
                                                u16* __restrict__ VT0) {
    int st = blockIdx.x, bh = blockIdx.y, z = blockIdx.z;
    const u16* src = Vrow + (size_t)z * EL + ((size_t)bh << 16) + (size_t)st * 64 * 64;
    u16* dst = VT0 + (size_t)z * 3 * EL + ((size_t)bh << 16) + st * 64;
    __shared__ u16 tile[64][72];
    int tid = threadIdx.x;
    int r = tid >> 2, c = (tid & 3) << 4;
    const u16* ip = src + (size_t)r * 64 + c;
    u16x8 a = *(const u16x8*)ip;
    u16x8 b = *(const u16x8*)(ip + 8);
#pragma unroll
    for (int e = 0; e < 8; ++e) { tile[r][c + e] = a[e]; tile[r][c + 8 + e] = b[e]; }
    __syncthreads();
    u16x8 o0, o1;
#pragma unroll
    for (int e = 0; e < 8; ++e) { o0[e] = tile[c + e][r]; o1[e] = tile[c + 8 + e][r]; }
    u16* op = dst + (size_t)r * 1024 + c;
    *(u16x8*)op = o0;
    *(u16x8*)(op + 8) = o1;
}

// ------- LayerNorm D=768, f32 in, bf16 out; 2-batch via blockIdx.y ----------
__global__ __launch_bounds__(256) void ln_k(const float* __restrict__ inX,
                                            const float* __restrict__ inY,
                                            const float* gX, const float* bX,
                                            const float* gY, const float* bY,
                                            u16* __restrict__ out0) {
    int z = blockIdx.y;
    const float* in = z ? inY : inX;
    const float* g = z ? gY : gX;
    const float* be = z ? bY : bX;
    u16* out = out0 + (size_t)z * EL;
    int row = blockIdx.x, tid = threadIdx.x;
    const float* p = in + (size_t)row * 768;
    float v0 = p[tid], v1 = p[tid + 256], v2 = p[tid + 512];
    float s = v0 + v1 + v2;
    float q = v0 * v0 + v1 * v1 + v2 * v2;
#pragma unroll
    for (int m = 1; m < 64; m <<= 1) { s += __shfl_xor(s, m); q += __shfl_xor(q, m); }
    __shared__ float red[8];
    int w = tid >> 6, lane = tid & 63;
    if (lane == 0) { red[w] = s; red[4 + w] = q; }
    __syncthreads();
    s = red[0] + red[1] + red[2] + red[3];
    q = red[4] + red[5] + red[6] + red[7];
    float mean = s * (1.0f / 768.0f);
    float var = q * (1.0f / 768.0f) - mean * mean;
    float rstd = rsqrtf(var + 1e-6f);
    u16* o = out + (size_t)row * 768;
    o[tid]       = f2bf((v0 - mean) * rstd * g[tid]       + be[tid]);
    o[tid + 256] = f2bf((v1 - mean) * rstd * g[tid + 256] + be[tid + 256]);
    o[tid + 512] = f2bf((v2 - mean) * rstd * g[tid + 512] + be[tid + 512]);
}

// ------- LayerNorm D=768, bf16 in, bf16 out (LN2 on x1/y1) ------------------
__global__ __launch_bounds__(256) void lnb_k(const u16* __restrict__ inX,
                                             const u16* __restrict__ inY,
                                             const float* gX, const float* bX,
                                             const float* gY, const float* bY,
                                             u16* __restrict__ out0) {
    int z = blockIdx.y;
    const u16* in = z ? inY : inX;
    const float* g = z ? gY : gX;
    const float* be = z ? bY : bX;
    u16* out = out0 + (size_t)z * EL;
    int row = blockIdx.x, tid = threadIdx.x;
    const u16* p = in + (size_t)row * 768;
    float v0 = b2f(p[tid]), v1 = b2f(p[tid + 256]), v2 = b2f(p[tid + 512]);
    float s = v0 + v1 + v2;
    float q = v0 * v0 + v1 * v1 + v2 * v2;
#pragma unroll
    for (int m = 1; m < 64; m <<= 1) { s += __shfl_xor(s, m); q += __shfl_xor(q, m); }
    __shared__ float red[8];
    int w = tid >> 6, lane = tid & 63;
    if (lane == 0) { red[w] = s; red[4 + w] = q; }
    __syncthreads();
    s = red[0] + red[1] + red[2] + red[3];
    q = red[4] + red[5] + red[6] + red[7];
    float mean = s * (1.0f / 768.0f);
    float var = q * (1.0f / 768.0f) - mean * mean;
    float rstd = rsqrtf(var + 1e-6f);
    u16* o = out + (size_t)row * 768;
    o[tid]       = f2bf((v0 - mean) * rstd * g[tid]       + be[tid]);
    o[tid + 256] = f2bf((v1 - mean) * rstd * g[tid + 256] + be[tid + 256]);
    o[tid + 512] = f2bf((v2 - mean) * rstd * g[tid + 512] + be[tid + 512]);
}

// ------- blend, 2-batch: a[z] = w1[z]*a[z] + w2[z]*b[z] ----------------------
__global__ __launch_bounds__(256) void blend_k(u16* __restrict__ a0,
                                               const u16* __restrict__ b0,
                                               const float* w11, const float* w12,
                                               const float* w21, const float* w22,
                                               int n8) {
    int z = blockIdx.z;
    u16* a = a0 + (size_t)z * EL;
    const u16* b = b0 + (size_t)z * EL;
    float wa = z ? *w21 : *w11, wb = z ? *w22 : *w12;
    for (int i = blockIdx.x * blockDim.x + threadIdx.x; i < n8;
         i += gridDim.x * blockDim.x) {
        u16x8 va = ((const u16x8*)a)[i];
        u16x8 vb = ((const u16x8*)b)[i];
        u16x8 r;
#pragma unroll
        for (int e = 0; e < 8; ++e) r[e] = f2bf(wa * b2f(va[e]) + wb * b2f(vb[e]));
        ((u16x8*)a)[i] = r;
    }
}

// ------- split-K combine: out = sum(parts) + b2[n] + x1(bf16) ----------------
__global__ __launch_bounds__(256) void combine_k(const float* __restrict__ parts,
                                                 int KS,
                                                 const u16* __restrict__ x1b,
                                                 const float* __restrict__ b2X,
                                                 const float* __restrict__ b2Y,
                                                 float* __restrict__ out, int n4tot) {
    int i = blockIdx.x * 256 + threadIdx.x;
    if (i >= n4tot) return;
    size_t e = (size_t)i * 4;
    f32x4 s = ((const f32x4*)parts)[i];
    for (int k = 1; k < KS; ++k)
        s += ((const f32x4*)(parts + (size_t)k * 2 * EL))[i];
    const float* bb = (e < EL) ? b2X : b2Y;
    int n = (int)(e % 768);
    ushort4 xv = ((const ushort4*)x1b)[i];
    f32x4 r;
    r[0] = s[0] + bb[n]     + b2f(xv.x);
    r[1] = s[1] + bb[n + 1] + b2f(xv.y);
    r[2] = s[2] + bb[n + 2] + b2f(xv.z);
    r[3] = s[3] + bb[n + 3] + b2f(xv.w);
    ((f32x4*)out)[i] = r;
}

#define EPI_GELU 3
#define EPI_WO 4     // resid f32 (X/Y), bias*(wa+wb), out bf16 (x1/y1)
#define EPI_MLP2 5   // resid bf16 (x1/y1), +bias, out f32 (d_out)
#define EPI_PART 6   // split-K partial: plain f32 store to parts[ks][z]

// ------- GEMM BM=128 BN=128 BK=32, 1D grid + xcd_map, optional split-K -------
template <int EPI>
__global__ __launch_bounds__(256) void gemm_k(
    const u16* __restrict__ A0, size_t Asz,
    const u16* __restrict__ B0, size_t Bsz,
    const float* __restrict__ bias0, const float* __restrict__ bias1,
    const void* __restrict__ r0, const void* __restrict__ r1,
    const float* s1a, const float* s1b, const float* s2a, const float* s2b,
    void* __restrict__ C0, size_t Csz,
    int M, int N, int K, int NN, int KS) {
    int m_, n_, z, ks;
    xcd_map(NN, m_, n_, z, ks);
    const int Kloc = K / KS;
    const u16* A = A0 + z * Asz;
    const u16* BT = B0 + z * Bsz;
    const float* bias = z ? bias1 : bias0;
    const float* residf = (const float*)(z ? r1 : r0);
    const u16* residb = (const u16*)(z ? r1 : r0);
    u16* Cb = (u16*)C0 + z * Csz;
    float* Cf = (float*)C0 + ((size_t)ks * 2 + z) * Csz;
    __shared__ u16 lA[2][4096];
    __shared__ u16 lB[2][4096];
    int tid = threadIdx.x;
    int bm0 = m_ << 7, bn0 = n_ << 7;
    int lane = tid & 63, wid = tid >> 6;
    int fr = lane & 15, g = lane >> 4;
    int wm = wid >> 1, wn = wid & 1;
    const u16* srcA0 = A + (size_t)(bm0 + (tid & 127)) * K + ks * Kloc + ((tid >> 7) << 3);
    const u16* srcA1 = srcA0 + 16;
    const u16* srcB0 = BT + (size_t)(bn0 + (tid & 127)) * K + ks * Kloc + ((tid >> 7) << 3);
    const u16* srcB1 = srcB0 + 16;
    auto STAGE = [&](int buf, int k0) {
        gld16(srcA0 + k0, &lA[buf][0] + tid * 8);
        gld16(srcA1 + k0, &lA[buf][0] + 2048 + tid * 8);
        gld16(srcB0 + k0, &lB[buf][0] + tid * 8);
        gld16(srcB1 + k0, &lB[buf][0] + 2048 + tid * 8);
    };
    f32x4 acc[4][4] = {};
    STAGE(0, 0);
    __syncthreads();
    int cur = 0;
    for (int k0 = 0; k0 < Kloc; k0 += 32) {
        if (k0 + 32 < Kloc) STAGE(cur ^ 1, k0 + 32);
        s16x8 af[4], bf[4];
#pragma unroll
        for (int i = 0; i < 4; ++i)
            af[i] = *(const s16x8*)&lA[cur][(g * 128 + wm * 64 + i * 16 + fr) * 8];
#pragma unroll
        for (int j = 0; j < 4; ++j)
            bf[j] = *(const s16x8*)&lB[cur][(g * 128 + wn * 64 + j * 16 + fr) * 8];
#pragma unroll
        for (int i = 0; i < 4; ++i)
#pragma unroll
            for (int j = 0; j < 4; ++j)
                acc[i][j] = mfma16(af[i], bf[j], acc[i][j]);
        __syncthreads();
        cur ^= 1;
    }
    float bscale = 1.0f;
    if (EPI == EPI_WO) bscale = z ? (s2a[0] + s2b[0]) : (s1a[0] + s1b[0]);
#pragma unroll
    for (int j = 0; j < 4; ++j) {
        int n = bn0 + wn * 64 + j * 16 + fr;
        float bv = 0.0f;
        if (EPI != EPI_PART) bv = bias[n] * bscale;
#pragma unroll
        for (int i = 0; i < 4; ++i) {
#pragma unroll
            for (int r = 0; r < 4; ++r) {
                int m = bm0 + wm * 64 + i * 16 + (g << 2) + r;
                size_t idx = (size_t)m * N + n;
                float v = acc[i][j][r] + bv;
                if (EPI == EPI_GELU) {
                    Cb[idx] = f2bf(gelu_f(v));
                } else if (EPI == EPI_WO) {
                    Cb[idx] = f2bf(v + residf[idx]);
                } else if (EPI == EPI_MLP2) {
                    Cf[idx] = v + b2f(residb[idx]);
                } else {
                    Cf[idx] = v;   // EPI_PART: partial, combined later
                }
            }
        }
    }
}

// ------- fused QKV GEMM. Q pre-scaled by 0.125*log2(e). ----------------------
// ALL segments store row-major head-split [B,H,S,64]; V transposed afterwards.
__global__ __launch_bounds__(256) void gemm_qkv_k(const u16* __restrict__ A0,
                                                  const u16* __restrict__ B0,
                                                  const float* bq, const float* bk,
                                                  const float* bv, const float* bqd,
                                                  const float* bkd, const float* bvd,
                                                  u16* __restrict__ Qd,
                                                  u16* __restrict__ Kd,
                                                  u16* __restrict__ Vd) {
    const int K = 768;
    int m_, n_, z, ks_;
    xcd_map(18, m_, n_, z, ks_);
    const u16* A = A0 + z * EL;
    const u16* BT = B0 + z * 3 * DDE;
    __shared__ u16 lA[2][4096];
    __shared__ u16 lB[2][4096];
    int tid = threadIdx.x;
    int bm0 = m_ << 7, bn0 = n_ << 7;
    int lane = tid & 63, wid = tid >> 6, wm = wid >> 1, wn = wid & 1;
    int fr = lane & 15, g = lane >> 4;
    const u16* srcA0 = A + (size_t)(bm0 + (tid & 127)) * K + ((tid >> 7) << 3);
    const u16* srcA1 = srcA0 + 16;
    const u16* srcB0 = BT + (size_t)(bn0 + (tid & 127)) * K + ((tid >> 7) << 3);
    const u16* srcB1 = srcB0 + 16;
    auto STAGE = [&](int buf, int k0) {
        gld16(srcA0 + k0, &lA[buf][0] + tid * 8);
        gld16(srcA1 + k0, &lA[buf][0] + 2048 + tid * 8);
        gld16(srcB0 + k0, &lB[buf][0] + tid * 8);
        gld16(srcB1 + k0, &lB[buf][0] + 2048 + tid * 8);
    };
    f32x4 acc[4][4] = {};
    STAGE(0, 0);
    __syncthreads();
    int cur = 0;
    for (int k0 = 0; k0 < K; k0 += 32) {
        if (k0 + 32 < K) STAGE(cur ^ 1, k0 + 32);
        s16x8 af[4], bf[4];
#pragma unroll
        for (int i = 0; i < 4; ++i)
            af[i] = *(const s16x8*)&lA[cur][(g * 128 + wm * 64 + i * 16 + fr) * 8];
#pragma unroll
        for (int j = 0; j < 4; ++j)
            bf[j] = *(const s16x8*)&lB[cur][(g * 128 + wn * 64 + j * 16 + fr) * 8];
#pragma unroll
        for (int i = 0; i < 4; ++i)
#pragma unroll
            for (int j = 0; j < 4; ++j)
                acc[i][j] = mfma16(af[i], bf[j], acc[i][j]);
        __syncthreads();
        cur ^= 1;
    }
    int seg = bn0 / 768;
    const float* bp = seg == 0 ? (z ? bqd : bq) : seg == 1 ? (z ? bkd : bk) : (z ? bvd : bv);
    u16* out;
    size_t zoff;
    if (seg == 0)      { out = Qd; zoff = (size_t)z * 3 * EL; }
    else if (seg == 1) { out = Kd; zoff = (size_t)z * 3 * EL; }
    else               { out = Vd; zoff = (size_t)z * EL; }
    int nbase = bn0 - seg * 768;
    const float qs = (seg == 0) ? 0.180336880f : 1.0f;  // 0.125 * log2(e)
#pragma unroll
    for (int j = 0; j < 4; ++j) {
        int nn = nbase + wn * 64 + j * 16 + fr;
        float bvl = bp[nn];
        int hh = nn >> 6, hd = nn & 63;
#pragma unroll
        for (int i = 0; i < 4; ++i) {
#pragma unroll
            for (int r = 0; r < 4; ++r) {
                int m = bm0 + wm * 64 + i * 16 + (g << 2) + r;
                int bb = m >> 10, ss = m & 1023;
                size_t o = zoff + (((size_t)(bb * 12 + hh)) << 16) + ((size_t)ss << 6) + hd;
                out[o] = f2bf((acc[i][j][r] + bvl) * qs);
            }
        }
    }
}

// ------- fused attention v6: 512 threads, 2 wave-groups share staged K/V -----
// Waves 0-3 compute config A of a K/V-sharing pair, waves 4-7 config B, against
// the SAME LDS K/V tiles (per-thread register state unchanged vs v4).
// KVBLK=64; swapped-QK^T register-shuffle P path.
__global__ __launch_bounds__(512) void attn_k(const u16* __restrict__ Qx,
                                              const u16* __restrict__ Kx,
                                              const u16* __restrict__ VTx,
                                              const u16* __restrict__ Qy,
                                              const u16* __restrict__ Ky,
                                              const u16* __restrict__ VTy,
                                              u16* __restrict__ csx,
                                              u16* __restrict__ ccx,
                                              u16* __restrict__ csy,
                                              u16* __restrict__ ccy) {
    int p = blockIdx.x;
    int lg = (p & 7) * 96 + (p >> 3);        // 96 logical ids per XCD
    int sg = lg >> 3, qt = lg & 7;           // supergroup = (pair, bh)
    int pairi = sg / 48, bh = sg % 48;
    int tid = threadIdx.x, lane = tid & 63, wid = tid >> 6;
    int wg = wid >> 2, w = wid & 3;
    int cfg = pairi == 0 ? (wg ? 3 : 0) : (wg ? 2 : 1);
    const u16* Kh = (pairi ? Ky : Kx) + ((size_t)bh << 16);
    const u16* Vh = (pairi ? VTy : VTx) + ((size_t)bh << 16);
    const u16* Qp;
    u16* Op;
    if (cfg == 0)      { Qp = Qx; Op = csx; }
    else if (cfg == 1) { Qp = Qy; Op = csy; }
    else if (cfg == 2) { Qp = Qx; Op = ccx; }
    else               { Qp = Qy; Op = ccy; }
    const u16* Qh = Qp + ((size_t)bh << 16);
    int b = bh / 12, h = bh % 12;
    int q0 = qt * 128 + w * 32;
    int fr = lane & 15, ko = (lane >> 4) << 3, g = lane >> 4;
    bool glo = lane < 32;
    int srcA = fr + ((lane & 16) << 1);
    int srcB = srcA + 16;

    __shared__ u16 kls[4096];   // 2 x (32 keys x 64 d), chunks XOR-swizzled
    __shared__ u16 vls[4096];   // 2 x (64 d x 32 keys), linear

    s16x8 qf[2][2];
#pragma unroll
    for (int s = 0; s < 2; ++s) {
        const u16* qp = Qh + (size_t)(q0 + s * 16 + fr) * 64 + ko;
        qf[s][0] = *(const s16x8*)qp;
        qf[s][1] = *(const s16x8*)(qp + 32);
    }

    f32x4 acc[2][4] = {};
    float lsum[2] = {0.f, 0.f};
    f32x4 zz = {0.f, 0.f, 0.f, 0.f};

    // staging: 512 threads, 1 K-chunk + 1 V-chunk each (16B); same LDS layout
    int half = tid >> 8, tt = tid & 255;
    int krow = tt >> 3, kpc = tt & 7;
    int kgc = kpc ^ (krow & 7);
    int vdr = tt >> 2, vpv = tt & 3;
    int lbase = half * 2048 + tt * 8;
    int cK0 = ((fr << 3) + (g ^ (fr & 7))) << 3;
    int cK1 = ((fr << 3) + ((g + 4) ^ (fr & 7))) << 3;
    int cK2 = (((fr + 16) << 3) + (g ^ (fr & 7))) << 3;
    int cK3 = (((fr + 16) << 3) + ((g + 4) ^ (fr & 7))) << 3;

    auto HALF = [&](int base) {
        s16x8 Kf0 = *(const s16x8*)&kls[base + cK0];
        s16x8 Kf1 = *(const s16x8*)&kls[base + cK1];
        s16x8 Kf2 = *(const s16x8*)&kls[base + cK2];
        s16x8 Kf3 = *(const s16x8*)&kls[base + cK3];
        s16x8 Vf[4];
#pragma unroll
        for (int t4 = 0; t4 < 4; ++t4)
            Vf[t4] = *(const s16x8*)&vls[base + ((t4 * 16 + fr) << 5) + (g << 3)];
        s16x8 pa[2];
#pragma unroll
        for (int s = 0; s < 2; ++s) {
            __builtin_amdgcn_s_setprio(1);
            f32x4 t0 = mfma16(Kf0, qf[s][0], zz);
            t0 = mfma16(Kf1, qf[s][1], t0);
            f32x4 t1 = mfma16(Kf2, qf[s][0], zz);
            t1 = mfma16(Kf3, qf[s][1], t1);
            __builtin_amdgcn_s_setprio(0);
            float p00 = EXP2(t0[0]), p01 = EXP2(t0[1]);
            float p02 = EXP2(t0[2]), p03 = EXP2(t0[3]);
            float p10 = EXP2(t1[0]), p11 = EXP2(t1[1]);
            float p12 = EXP2(t1[2]), p13 = EXP2(t1[3]);
            lsum[s] += (p00 + p01 + p02 + p03) + (p10 + p11 + p12 + p13);
            unsigned w0, w1, w2, w3;
            asm("v_cvt_pk_bf16_f32 %0, %1, %2" : "=v"(w0) : "v"(p00), "v"(p01));
            asm("v_cvt_pk_bf16_f32 %0, %1, %2" : "=v"(w1) : "v"(p02), "v"(p03));
            asm("v_cvt_pk_bf16_f32 %0, %1, %2" : "=v"(w2) : "v"(p10), "v"(p11));
            asm("v_cvt_pk_bf16_f32 %0, %1, %2" : "=v"(w3) : "v"(p12), "v"(p13));
            int e0 = __shfl((int)w0, srcA), e1 = __shfl((int)w1, srcA);
            int e2 = __shfl((int)w0, srcB), e3 = __shfl((int)w1, srcB);
            int f0 = __shfl((int)w2, srcA), f1 = __shfl((int)w3, srcA);
            int f2 = __shfl((int)w2, srcB), f3 = __shfl((int)w3, srcB);
            int4 wd;
            wd.x = glo ? e0 : f0;
            wd.y = glo ? e1 : f1;
            wd.z = glo ? e2 : f2;
            wd.w = glo ? e3 : f3;
            pa[s] = __builtin_bit_cast(s16x8, wd);
        }
        __builtin_amdgcn_s_setprio(1);
#pragma unroll
        for (int t4 = 0; t4 < 4; ++t4) {
            acc[0][t4] = mfma16(pa[0], Vf[t4], acc[0][t4]);
            acc[1][t4] = mfma16(pa[1], Vf[t4], acc[1][t4]);
        }
        __builtin_amdgcn_s_setprio(0);
    };

    for (int kb = 0; kb < 1024; kb += 64) {
        gld16(Kh + (size_t)(kb + half * 32 + krow) * 64 + kgc * 8, &kls[lbase]);
        gld16(Vh + (size_t)vdr * 1024 + kb + half * 32 + vpv * 8, &vls[lbase]);
        __syncthreads();   // drains vmcnt: both sub-tiles ready
        HALF(0);
        HALF(2048);
        __syncthreads();   // all reads done before next stage overwrites
    }

    float invv[2][4];
#pragma unroll
    for (int s = 0; s < 2; ++s) {
        float l = lsum[s];
        l += __shfl_xor(l, 16);
        l += __shfl_xor(l, 32);
        float inv = 1.0f / l;
#pragma unroll
        for (int r = 0; r < 4; ++r)
            invv[s][r] = __shfl(inv, ((lane >> 4) << 2) + r);
    }
#pragma unroll
    for (int s = 0; s < 2; ++s) {
        u16* ob = Op + (size_t)(b * 1024 + q0 + s * 16 + ((lane >> 4) << 2)) * 768 + h * 64 + fr;
#pragma unroll
        for (int t4 = 0; t4 < 4; ++t4)
#pragma unroll
            for (int r = 0; r < 4; ++r)
                ob[(size_t)r * 768 + t4 * 16] = f2bf(acc[s][t4][r] * invv[s][r]);
    }
}

// -----------------------------------------------------------------------------
extern "C" void kernel_launch(void* const* d_in, const int* in_sizes, int n_in,
                              void* d_out, int out_size, void* d_ws, size_t ws_size,
                              hipStream_t stream) {
    (void)in_sizes; (void)n_in; (void)out_size;
    const float* X    = (const float*)d_in[0];
    const float* Y    = (const float*)d_in[1];
    const float* l1xg = (const float*)d_in[2];
    const float* l1xb = (const float*)d_in[3];
    const float* l1yg = (const float*)d_in[4];
    const float* l1yb = (const float*)d_in[5];
    const float* Wq   = (const float*)d_in[6];
    const float* bq   = (const float*)d_in[7];
    const float* Wk   = (const float*)d_in[8];
    const float* bk   = (const float*)d_in[9];
    const float* Wv   = (const float*)d_in[10];
    const float* bv   = (const float*)d_in[11];
    const float* Wo   = (const float*)d_in[12];
    const float* bo   = (const float*)d_in[13];
    const float* Wqd  = (const float*)d_in[14];
    const float* bqd  = (const float*)d_in[15];
    const float* Wkd  = (const float*)d_in[16];
    const float* bkd  = (const float*)d_in[17];
    const float* Wvd  = (const float*)d_in[18];
    const float* bvd  = (const float*)d_in[19];
    const float* Wod  = (const float*)d_in[20];
    const float* bod  = (const float*)d_in[21];
    const float* w11  = (const float*)d_in[22];
    const float* w12  = (const float*)d_in[23];
    const float* w21  = (const float*)d_in[24];
    const float* w22  = (const float*)d_in[25];
    const float* l2xg = (const float*)d_in[26];
    const float* l2xb = (const float*)d_in[27];
    const float* l2yg = (const float*)d_in[28];
    const float* l2yb = (const float*)d_in[29];
    const float* W1   = (const float*)d_in[30];
    const float* b1   = (const float*)d_in[31];
    const float* W2   = (const float*)d_in[32];
    const float* b2   = (const float*)d_in[33];
    const float* W1d  = (const float*)d_in[34];
    const float* b1d  = (const float*)d_in[35];
    const float* W2d  = (const float*)d_in[36];
    const float* b2d  = (const float*)d_in[37];

    u16* ws = (u16*)d_ws;
    u16* qkvT = ws;
    u16* WoT  = qkvT + 6 * DDE;
    u16* W1T  = WoT + 2 * DDE;
    u16* W2T  = W1T + 2 * DFE;
    u16* xn   = W2T + 2 * DFE;   // 2E: xn,yn (also LN2 outs later)
    u16* Qx   = xn + 2 * EL;     // 6E: Qx,Kx,VTx,Qy,Ky,VTy ; h aliases (8E)
    u16* cs   = Qx + 6 * EL;     // 4E: csx,csy,ccx,ccy (also Vrow scratch)
    u16* x1   = cs + 4 * EL;     // 2E bf16: x1,y1
    u16* Kx = Qx + EL;
    u16* VTx = Qx + 2 * EL;
    u16* h = Qx;                 // MLP hidden: x at h, y at h+4E
    u16* y1 = x1 + EL;
    u16* wsEnd = x1 + 2 * EL;    // end of fixed layout
    u16* Vrow = cs;              // V row-major scratch (2E), dead before attn writes cs

    float* out_x = (float*)d_out;

    float* parts = (float*)wsEnd;
    size_t baseBytes = (size_t)(wsEnd - ws) * 2;
    size_t partBytes = 2 * EL * sizeof(float);
    int KS = 1;
    if (ws_size >= baseBytes + 4 * partBytes) KS = 4;
    else if (ws_size >= baseBytes + 2 * partBytes) KS = 2;

    dim3 tb(256);
    transpose8_k<<<dim3(12, 12, 8), tb, 0, stream>>>(Wq, Wk, Wv, Wqd, Wkd, Wvd, Wo, Wod, qkvT);
    transpose2_k<<<dim3(48, 12, 2), tb, 0, stream>>>(W1, W1d, W1T, DFE, 768, 3072);
    transpose2_k<<<dim3(12, 48, 2), tb, 0, stream>>>(W2, W2d, W2T, DFE, 3072, 768);
    ln_k<<<dim3(4096, 2), tb, 0, stream>>>(X, Y, l1xg, l1xb, l1yg, l1yb, xn);
    gemm_qkv_k<<<1152, tb, 0, stream>>>(xn, qkvT, bq, bk, bv, bqd, bkd, bvd,
                                        Qx, Kx, Vrow);
    vtrans_k<<<dim3(16, 48, 2), tb, 0, stream>>>(Vrow, VTx);
    // attn: 768 blocks x 512 threads = 2 pair x 48 bh x 8 qt, 2 cfgs per block
    attn_k<<<768, dim3(512), 0, stream>>>(Qx, Kx, VTx, Qx + 3 * EL, Qx + 4 * EL, Qx + 5 * EL,
                                          cs, cs + 2 * EL, cs + EL, cs + 3 * EL);
    int n8 = (int)(EL / 8);
    blend_k<<<dim3(1536, 1, 2), tb, 0, stream>>>(cs, cs + 2 * EL, w11, w12, w21, w22, n8);
    gemm_k<EPI_WO><<<384, tb, 0, stream>>>(
        cs, EL, WoT, DDE, bo, bod, X, Y, w11, w12, w21, w22, x1, EL,
        4096, 768, 768, 6, 1);
    lnb_k<<<dim3(4096, 2), tb, 0, stream>>>(x1, y1, l2xg, l2xb, l2yg, l2yb, xn);
    gemm_k<EPI_GELU><<<1536, tb, 0, stream>>>(
        xn, EL, W1T, DFE, b1, b1d, nullptr, nullptr, nullptr, nullptr, nullptr, nullptr,
        h, 4 * EL, 4096, 3072, 768, 24, 1);
    if (KS > 1) {
        gemm_k<EPI_PART><<<384 * KS, tb, 0, stream>>>(
            h, 4 * EL, W2T, DFE, nullptr, nullptr, nullptr, nullptr,
            nullptr, nullptr, nullptr, nullptr,
            parts, EL, 4096, 768, 3072, 6, KS);
        int n4 = (int)(2 * EL / 4);
        combine_k<<<(n4 + 255) / 256, tb, 0, stream>>>(parts, KS, x1, b2, b2d,
                                                       out_x, n4);
    } else {
        gemm_k<EPI_MLP2><<<384, tb, 0, stream>>>(
            h, 4 * EL, W2T, DFE, b2, b2d, x1, y1,
            nullptr, nullptr, nullptr, nullptr,
            out_x, EL, 4096, 768, 3072, 6, 1);
    }
}

// Round 21
// 436.118 us; speedup vs baseline: 1.0028x; 1.0028x over previous
//
#include <hip/hip_runtime.h>

typedef unsigned short u16;
typedef unsigned short u16x8 __attribute__((ext_vector_type(8)));
typedef short s16x8 __attribute__((ext_vector_type(8)));
typedef float f32x4 __attribute__((ext_vector_type(4)));

#define EL ((size_t)3145728)       // 4096*768
#define DDE ((size_t)589824)       // 768*768
#define DFE ((size_t)2359296)      // 768*3072

#if __has_builtin(__builtin_amdgcn_exp2f)
#define EXP2(x) __builtin_amdgcn_exp2f(x)
#else
#define EXP2(x) __expf((x) * 0.6931471805599453f)
#endif

__device__ __forceinline__ float b2f(u16 u) {
    return __builtin_bit_cast(float, (unsigned)u << 16);
}
__device__ __forceinline__ u16 f2bf(float f) {
    unsigned x = __builtin_bit_cast(unsigned, f);
    return (u16)((x + 0x7fffu + ((x >> 16) & 1u)) >> 16);
}
__device__ __forceinline__ float gelu_f(float x) {
    float t = x + 0.044715f * x * x * x;
    return x * __builtin_amdgcn_rcpf(1.0f + EXP2(-2.302207417f * t));
}
__device__ __forceinline__ f32x4 mfma16(s16x8 a, s16x8 b, f32x4 c) {
    return __builtin_amdgcn_mfma_f32_16x16x32_bf16(a, b, c, 0, 0, 0);
}
__device__ __forceinline__ void gld16(const u16* g, u16* l) {
    __builtin_amdgcn_global_load_lds((const __attribute__((address_space(1))) void*)g,
                                     (__attribute__((address_space(3))) void*)l,
                                     16, 0, 0);
}
// XCD panel-ownership map: 1D grid T (T%8==0, (T/8)%NN==0).
__device__ __forceinline__ void xcd_map(int NN, int& m, int& n, int& z, int& ks) {
    int p = blockIdx.x, T = gridDim.x;
    int ppx = T >> 3;
    int xcd = p & 7, l = p >> 3;
    int panel = l / NN;
    n = l - panel * NN;
    int gp = xcd * (ppx / NN) + panel;
    m = gp & 31;
    z = (gp >> 5) & 1;
    ks = gp >> 6;
}

// ------- transpose+cast, 8-batch (768x768 each): z selects src; dst+z*DDE ----
__global__ __launch_bounds__(256) void transpose8_k(const float* p0, const float* p1,
                                                    const float* p2, const float* p3,
                                                    const float* p4, const float* p5,
                                                    const float* p6, const float* p7,
                                                    u16* __restrict__ dst0) {
    int z = blockIdx.z;
    const float* in = z == 0 ? p0 : z == 1 ? p1 : z == 2 ? p2 : z == 3 ? p3
                    : z == 4 ? p4 : z == 5 ? p5 : z == 6 ? p6 : p7;
    u16* out = dst0 + (size_t)z * DDE;
    const int K = 768, N = 768;
    __shared__ u16 tile[64][72];
    int k0 = blockIdx.y << 6, n0 = blockIdx.x << 6;
    int tid = threadIdx.x;
    int r = tid >> 2, c = (tid & 3) << 4;
    const float* ip = in + (size_t)(k0 + r) * N + n0 + c;
#pragma unroll
    for (int q = 0; q < 4; ++q) {
        f32x4 v = *(const f32x4*)(ip + 4 * q);
#pragma unroll
        for (int e = 0; e < 4; ++e) tile[r][c + 4 * q + e] = f2bf(v[e]);
    }
    __syncthreads();
    u16x8 o0, o1;
#pragma unroll
    for (int e = 0; e < 8; ++e) { o0[e] = tile[c + e][r]; o1[e] = tile[c + 8 + e][r]; }
    u16* op = out + (size_t)(n0 + r) * K + k0 + c;
    *(u16x8*)op = o0;
    *(u16x8*)(op + 8) = o1;
}

// ------- transpose+cast, 2-batch: in [K][N] f32 -> out bf16 [N][K] -----------
__global__ __launch_bounds__(256) void transpose2_k(const float* pa, const float* pb,
                                                    u16* __restrict__ dst0, size_t dsz,
                                                    int K, int N) {
    int z = blockIdx.z;
    const float* in = z ? pb : pa;
    u16* out = dst0 + (size_t)z * dsz;
    __shared__ u16 tile[64][72];
    int k0 = blockIdx.y << 6, n0 = blockIdx.x << 6;
    int tid = threadIdx.x;
    int r = tid >> 2, c = (tid & 3) << 4;
    const float* ip = in + (size_t)(k0 + r) * N + n0 + c;
#pragma unroll
    for (int q = 0; q < 4; ++q) {
        f32x4 v = *(const f32x4*)(ip + 4 * q);
#pragma unroll
        for (int e = 0; e < 4; ++e) tile[r][c + 4 * q + e] = f2bf(v[e]);
    }
    __syncthreads();
    u16x8 o0, o1;
#pragma unroll
    for (int e = 0; e < 8; ++e) { o0[e] = tile[c + e][r]; o1[e] = tile[c + 8 + e][r]; }
    u16* op = out + (size_t)(n0 + r) * K + k0 + c;
    *(u16x8*)op = o0;
    *(u16x8*)(op + 8) = o1;
}

// ------- V row-major [B,H,S,64] -> VT [B,H,64,S]; grid (16 st, 48 bh, 2 z) ---
__global__ __launch_bounds__(256) void vtrans_k(const u16* __restrict__ Vrow,
                                                u16* __restrict__ VT0) {
    int st = blockIdx.x, bh = blockIdx.y, z = blockIdx.z;
    const u16* src = Vrow + (size_t)z * EL + ((size_t)bh << 16) + (size_t)st * 64 * 64;
    u16* dst = VT0 + (size_t)z * 3 * EL + ((size_t)bh << 16) + st * 64;
    __shared__ u16 tile[64][72];
    int tid = threadIdx.x;
    int r = tid >> 2, c = (tid & 3) << 4;
    const u16* ip = src + (size_t)r * 64 + c;
    u16x8 a = *(const u16x8*)ip;
    u16x8 b = *(const u16x8*)(ip + 8);
#pragma unroll
    for (int e = 0; e < 8; ++e) { tile[r][c + e] = a[e]; tile[r][c + 8 + e] = b[e]; }
    __syncthreads();
    u16x8 o0, o1;
#pragma unroll
    for (int e = 0; e < 8; ++e) { o0[e] = tile[c + e][r]; o1[e] = tile[c + 8 + e][r]; }
    u16* op = dst + (size_t)r * 1024 + c;
    *(u16x8*)op = o0;
    *(u16x8*)(op + 8) = o1;
}

// ------- LayerNorm D=768, f32 in, bf16 out; 2-batch via blockIdx.y ----------
__global__ __launch_bounds__(256) void ln_k(const float* __restrict__ inX,
                                            const float* __restrict__ inY,
                                            const float* gX, const float* bX,
                                            const float* gY, const float* bY,
                                            u16* __restrict__ out0) {
    int z = blockIdx.y;
    const float* in = z ? inY : inX;
    const float* g = z ? gY : gX;
    const float* be = z ? bY : bX;
    u16* out = out0 + (size_t)z * EL;
    int row = blockIdx.x, tid = threadIdx.x;
    const float* p = in + (size_t)row * 768;
    float v0 = p[tid], v1 = p[tid + 256], v2 = p[tid + 512];
    float s = v0 + v1 + v2;
    float q = v0 * v0 + v1 * v1 + v2 * v2;
#pragma unroll
    for (int m = 1; m < 64; m <<= 1) { s += __shfl_xor(s, m); q += __shfl_xor(q, m); }
    __shared__ float red[8];
    int w = tid >> 6, lane = tid & 63;
    if (lane == 0) { red[w] = s; red[4 + w] = q; }
    __syncthreads();
    s = red[0] + red[1] + red[2] + red[3];
    q = red[4] + red[5] + red[6] + red[7];
    float mean = s * (1.0f / 768.0f);
    float var = q * (1.0f / 768.0f) - mean * mean;
    float rstd = rsqrtf(var + 1e-6f);
    u16* o = out + (size_t)row * 768;
    o[tid]       = f2bf((v0 - mean) * rstd * g[tid]       + be[tid]);
    o[tid + 256] = f2bf((v1 - mean) * rstd * g[tid + 256] + be[tid + 256]);
    o[tid + 512] = f2bf((v2 - mean) * rstd * g[tid + 512] + be[tid + 512]);
}

// ------- LayerNorm D=768, bf16 in, bf16 out (LN2 on x1/y1) ------------------
__global__ __launch_bounds__(256) void lnb_k(const u16* __restrict__ inX,
                                             const u16* __restrict__ inY,
                                             const float* gX, const float* bX,
                                             const float* gY, const float* bY,
                                             u16* __restrict__ out0) {
    int z = blockIdx.y;
    const u16* in = z ? inY : inX;
    const float* g = z ? gY : gX;
    const float* be = z ? bY : bX;
    u16* out = out0 + (size_t)z * EL;
    int row = blockIdx.x, tid = threadIdx.x;
    const u16* p = in + (size_t)row * 768;
    float v0 = b2f(p[tid]), v1 = b2f(p[tid + 256]), v2 = b2f(p[tid + 512]);
    float s = v0 + v1 + v2;
    float q = v0 * v0 + v1 * v1 + v2 * v2;
#pragma unroll
    for (int m = 1; m < 64; m <<= 1) { s += __shfl_xor(s, m); q += __shfl_xor(q, m); }
    __shared__ float red[8];
    int w = tid >> 6, lane = tid & 63;
    if (lane == 0) { red[w] = s; red[4 + w] = q; }
    __syncthreads();
    s = red[0] + red[1] + red[2] + red[3];
    q = red[4] + red[5] + red[6] + red[7];
    float mean = s * (1.0f / 768.0f);
    float var = q * (1.0f / 768.0f) - mean * mean;
    float rstd = rsqrtf(var + 1e-6f);
    u16* o = out + (size_t)row * 768;
    o[tid]       = f2bf((v0 - mean) * rstd * g[tid]       + be[tid]);
    o[tid + 256] = f2bf((v1 - mean) * rstd * g[tid + 256] + be[tid + 256]);
    o[tid + 512] = f2bf((v2 - mean) * rstd * g[tid + 512] + be[tid + 512]);
}

// ------- blend, 2-batch: a[z] = w1[z]*a[z] + w2[z]*b[z] ----------------------
__global__ __launch_bounds__(256) void blend_k(u16* __restrict__ a0,
                                               const u16* __restrict__ b0,
                                               const float* w11, const float* w12,
                                               const float* w21, const float* w22,
                                               int n8) {
    int z = blockIdx.z;
    u16* a = a0 + (size_t)z * EL;
    const u16* b = b0 + (size_t)z * EL;
    float wa = z ? *w21 : *w11, wb = z ? *w22 : *w12;
    for (int i = blockIdx.x * blockDim.x + threadIdx.x; i < n8;
         i += gridDim.x * blockDim.x) {
        u16x8 va = ((const u16x8*)a)[i];
        u16x8 vb = ((const u16x8*)b)[i];
        u16x8 r;
#pragma unroll
        for (int e = 0; e < 8; ++e) r[e] = f2bf(wa * b2f(va[e]) + wb * b2f(vb[e]));
        ((u16x8*)a)[i] = r;
    }
}

// ------- split-K combine: out = sum(parts) + b2[n] + x1(bf16) ----------------
__global__ __launch_bounds__(256) void combine_k(const float* __restrict__ parts,
                                                 int KS,
                                                 const u16* __restrict__ x1b,
                                                 const float* __restrict__ b2X,
                                                 const float* __restrict__ b2Y,
                                                 float* __restrict__ out, int n4tot) {
    int i = blockIdx.x * 256 + threadIdx.x;
    if (i >= n4tot) return;
    size_t e = (size_t)i * 4;
    f32x4 s = ((const f32x4*)parts)[i];
    for (int k = 1; k < KS; ++k)
        s += ((const f32x4*)(parts + (size_t)k * 2 * EL))[i];
    const float* bb = (e < EL) ? b2X : b2Y;
    int n = (int)(e % 768);
    ushort4 xv = ((const ushort4*)x1b)[i];
    f32x4 r;
    r[0] = s[0] + bb[n]     + b2f(xv.x);
    r[1] = s[1] + bb[n + 1] + b2f(xv.y);
    r[2] = s[2] + bb[n + 2] + b2f(xv.z);
    r[3] = s[3] + bb[n + 3] + b2f(xv.w);
    ((f32x4*)out)[i] = r;
}

#define EPI_GELU 3
#define EPI_WO 4     // resid f32 (X/Y), bias*(wa+wb), out bf16 (x1/y1)
#define EPI_MLP2 5   // resid bf16 (x1/y1), +bias, out f32 (d_out)
#define EPI_PART 6   // split-K partial: plain f32 store to parts[ks][z]

// ------- GEMM BM=128 BN=128 BK=32, 1D grid + xcd_map, optional split-K -------
template <int EPI>
__global__ __launch_bounds__(256) void gemm_k(
    const u16* __restrict__ A0, size_t Asz,
    const u16* __restrict__ B0, size_t Bsz,
    const float* __restrict__ bias0, const float* __restrict__ bias1,
    const void* __restrict__ r0, const void* __restrict__ r1,
    const float* s1a, const float* s1b, const float* s2a, const float* s2b,
    void* __restrict__ C0, size_t Csz,
    int M, int N, int K, int NN, int KS) {
    int m_, n_, z, ks;
    xcd_map(NN, m_, n_, z, ks);
    const int Kloc = K / KS;
    const u16* A = A0 + z * Asz;
    const u16* BT = B0 + z * Bsz;
    const float* bias = z ? bias1 : bias0;
    const float* residf = (const float*)(z ? r1 : r0);
    const u16* residb = (const u16*)(z ? r1 : r0);
    u16* Cb = (u16*)C0 + z * Csz;
    float* Cf = (float*)C0 + ((size_t)ks * 2 + z) * Csz;
    __shared__ u16 lA[2][4096];
    __shared__ u16 lB[2][4096];
    int tid = threadIdx.x;
    int bm0 = m_ << 7, bn0 = n_ << 7;
    int lane = tid & 63, wid = tid >> 6;
    int fr = lane & 15, g = lane >> 4;
    int wm = wid >> 1, wn = wid & 1;
    const u16* srcA0 = A + (size_t)(bm0 + (tid & 127)) * K + ks * Kloc + ((tid >> 7) << 3);
    const u16* srcA1 = srcA0 + 16;
    const u16* srcB0 = BT + (size_t)(bn0 + (tid & 127)) * K + ks * Kloc + ((tid >> 7) << 3);
    const u16* srcB1 = srcB0 + 16;
    auto STAGE = [&](int buf, int k0) {
        gld16(srcA0 + k0, &lA[buf][0] + tid * 8);
        gld16(srcA1 + k0, &lA[buf][0] + 2048 + tid * 8);
        gld16(srcB0 + k0, &lB[buf][0] + tid * 8);
        gld16(srcB1 + k0, &lB[buf][0] + 2048 + tid * 8);
    };
    f32x4 acc[4][4] = {};
    STAGE(0, 0);
    __syncthreads();
    int cur = 0;
    for (int k0 = 0; k0 < Kloc; k0 += 32) {
        if (k0 + 32 < Kloc) STAGE(cur ^ 1, k0 + 32);
        s16x8 af[4], bf[4];
#pragma unroll
        for (int i = 0; i < 4; ++i)
            af[i] = *(const s16x8*)&lA[cur][(g * 128 + wm * 64 + i * 16 + fr) * 8];
#pragma unroll
        for (int j = 0; j < 4; ++j)
            bf[j] = *(const s16x8*)&lB[cur][(g * 128 + wn * 64 + j * 16 + fr) * 8];
#pragma unroll
        for (int i = 0; i < 4; ++i)
#pragma unroll
            for (int j = 0; j < 4; ++j)
                acc[i][j] = mfma16(af[i], bf[j], acc[i][j]);
        __syncthreads();
        cur ^= 1;
    }
    float bscale = 1.0f;
    if (EPI == EPI_WO) bscale = z ? (s2a[0] + s2b[0]) : (s1a[0] + s1b[0]);
#pragma unroll
    for (int j = 0; j < 4; ++j) {
        int n = bn0 + wn * 64 + j * 16 + fr;
        float bv = 0.0f;
        if (EPI != EPI_PART) bv = bias[n] * bscale;
#pragma unroll
        for (int i = 0; i < 4; ++i) {
#pragma unroll
            for (int r = 0; r < 4; ++r) {
                int m = bm0 + wm * 64 + i * 16 + (g << 2) + r;
                size_t idx = (size_t)m * N + n;
                float v = acc[i][j][r] + bv;
                if (EPI == EPI_GELU) {
                    Cb[idx] = f2bf(gelu_f(v));
                } else if (EPI == EPI_WO) {
                    Cb[idx] = f2bf(v + residf[idx]);
                } else if (EPI == EPI_MLP2) {
                    Cf[idx] = v + b2f(residb[idx]);
                } else {
                    Cf[idx] = v;   // EPI_PART: partial, combined later
                }
            }
        }
    }
}

// ------- fused QKV GEMM. Q pre-scaled by 0.125*log2(e). ----------------------
// ALL segments store row-major head-split [B,H,S,64]; V transposed afterwards.
__global__ __launch_bounds__(256) void gemm_qkv_k(const u16* __restrict__ A0,
                                                  const u16* __restrict__ B0,
                                                  const float* bq, const float* bk,
                                                  const float* bv, const float* bqd,
                                                  const float* bkd, const float* bvd,
                                                  u16* __restrict__ Qd,
                                                  u16* __restrict__ Kd,
                                                  u16* __restrict__ Vd) {
    const int K = 768;
    int m_, n_, z, ks_;
    xcd_map(18, m_, n_, z, ks_);
    const u16* A = A0 + z * EL;
    const u16* BT = B0 + z * 3 * DDE;
    __shared__ u16 lA[2][4096];
    __shared__ u16 lB[2][4096];
    int tid = threadIdx.x;
    int bm0 = m_ << 7, bn0 = n_ << 7;
    int lane = tid & 63, wid = tid >> 6, wm = wid >> 1, wn = wid & 1;
    int fr = lane & 15, g = lane >> 4;
    const u16* srcA0 = A + (size_t)(bm0 + (tid & 127)) * K + ((tid >> 7) << 3);
    const u16* srcA1 = srcA0 + 16;
    const u16* srcB0 = BT + (size_t)(bn0 + (tid & 127)) * K + ((tid >> 7) << 3);
    const u16* srcB1 = srcB0 + 16;
    auto STAGE = [&](int buf, int k0) {
        gld16(srcA0 + k0, &lA[buf][0] + tid * 8);
        gld16(srcA1 + k0, &lA[buf][0] + 2048 + tid * 8);
        gld16(srcB0 + k0, &lB[buf][0] + tid * 8);
        gld16(srcB1 + k0, &lB[buf][0] + 2048 + tid * 8);
    };
    f32x4 acc[4][4] = {};
    STAGE(0, 0);
    __syncthreads();
    int cur = 0;
    for (int k0 = 0; k0 < K; k0 += 32) {
        if (k0 + 32 < K) STAGE(cur ^ 1, k0 + 32);
        s16x8 af[4], bf[4];
#pragma unroll
        for (int i = 0; i < 4; ++i)
            af[i] = *(const s16x8*)&lA[cur][(g * 128 + wm * 64 + i * 16 + fr) * 8];
#pragma unroll
        for (int j = 0; j < 4; ++j)
            bf[j] = *(const s16x8*)&lB[cur][(g * 128 + wn * 64 + j * 16 + fr) * 8];
#pragma unroll
        for (int i = 0; i < 4; ++i)
#pragma unroll
            for (int j = 0; j < 4; ++j)
                acc[i][j] = mfma16(af[i], bf[j], acc[i][j]);
        __syncthreads();
        cur ^= 1;
    }
    int seg = bn0 / 768;
    const float* bp = seg == 0 ? (z ? bqd : bq) : seg == 1 ? (z ? bkd : bk) : (z ? bvd : bv);
    u16* out;
    size_t zoff;
    if (seg == 0)      { out = Qd; zoff = (size_t)z * 3 * EL; }
    else if (seg == 1) { out = Kd; zoff = (size_t)z * 3 * EL; }
    else               { out = Vd; zoff = (size_t)z * EL; }
    int nbase = bn0 - seg * 768;
    const float qs = (seg == 0) ? 0.180336880f : 1.0f;  // 0.125 * log2(e)
#pragma unroll
    for (int j = 0; j < 4; ++j) {
        int nn = nbase + wn * 64 + j * 16 + fr;
        float bvl = bp[nn];
        int hh = nn >> 6, hd = nn & 63;
#pragma unroll
        for (int i = 0; i < 4; ++i) {
#pragma unroll
            for (int r = 0; r < 4; ++r) {
                int m = bm0 + wm * 64 + i * 16 + (g << 2) + r;
                int bb = m >> 10, ss = m & 1023;
                size_t o = zoff + (((size_t)(bb * 12 + hh)) << 16) + ((size_t)ss << 6) + hd;
                out[o] = f2bf((acc[i][j][r] + bvl) * qs);
            }
        }
    }
}

// ------- fused attention v7: v6 + V-tile XOR swizzle (kills 8-way conflict) --
// 512 threads, 2 wave-groups share staged K/V; swapped-QK^T reg-shuffle P.
// V chunk permutation c' = c ^ ((row>>1)&3): applied on global SOURCE during
// staging (LDS dest linear, rule #21) and on the read address. Banks become
// (fr&1)*16 + (g^((fr>>1)&3))*4 -> 8 groups x 2 lanes = 2-way (free).
__global__ __launch_bounds__(512) void attn_k(const u16* __restrict__ Qx,
                                              const u16* __restrict__ Kx,
                                              const u16* __restrict__ VTx,
                                              const u16* __restrict__ Qy,
                                              const u16* __restrict__ Ky,
                                              const u16* __restrict__ VTy,
                                              u16* __restrict__ csx,
                                              u16* __restrict__ ccx,
                                              u16* __restrict__ csy,
                                              u16* __restrict__ ccy) {
    int p = blockIdx.x;
    int lg = (p & 7) * 96 + (p >> 3);        // 96 logical ids per XCD
    int sg = lg >> 3, qt = lg & 7;           // supergroup = (pair, bh)
    int pairi = sg / 48, bh = sg % 48;
    int tid = threadIdx.x, lane = tid & 63, wid = tid >> 6;
    int wg = wid >> 2, w = wid & 3;
    int cfg = pairi == 0 ? (wg ? 3 : 0) : (wg ? 2 : 1);
    const u16* Kh = (pairi ? Ky : Kx) + ((size_t)bh << 16);
    const u16* Vh = (pairi ? VTy : VTx) + ((size_t)bh << 16);
    const u16* Qp;
    u16* Op;
    if (cfg == 0)      { Qp = Qx; Op = csx; }
    else if (cfg == 1) { Qp = Qy; Op = csy; }
    else if (cfg == 2) { Qp = Qx; Op = ccx; }
    else               { Qp = Qy; Op = ccy; }
    const u16* Qh = Qp + ((size_t)bh << 16);
    int b = bh / 12, h = bh % 12;
    int q0 = qt * 128 + w * 32;
    int fr = lane & 15, ko = (lane >> 4) << 3, g = lane >> 4;
    bool glo = lane < 32;
    int srcA = fr + ((lane & 16) << 1);
    int srcB = srcA + 16;

    __shared__ u16 kls[4096];   // 2 x (32 keys x 64 d), chunks XOR-swizzled
    __shared__ u16 vls[4096];   // 2 x (64 d x 32 keys), chunks XOR-swizzled

    s16x8 qf[2][2];
#pragma unroll
    for (int s = 0; s < 2; ++s) {
        const u16* qp = Qh + (size_t)(q0 + s * 16 + fr) * 64 + ko;
        qf[s][0] = *(const s16x8*)qp;
        qf[s][1] = *(const s16x8*)(qp + 32);
    }

    f32x4 acc[2][4] = {};
    float lsum[2] = {0.f, 0.f};
    f32x4 zz = {0.f, 0.f, 0.f, 0.f};

    // staging: 512 threads, 1 K-chunk + 1 V-chunk each (16B); LDS dest linear
    int half = tid >> 8, tt = tid & 255;
    int krow = tt >> 3, kpc = tt & 7;
    int kgc = kpc ^ (krow & 7);              // K source-chunk swizzle
    int vdr = tt >> 2, vpv = tt & 3;
    int vgc = vpv ^ ((vdr >> 1) & 3);        // V source-chunk swizzle
    int lbase = half * 2048 + tt * 8;
    int cK0 = ((fr << 3) + (g ^ (fr & 7))) << 3;
    int cK1 = ((fr << 3) + ((g + 4) ^ (fr & 7))) << 3;
    int cK2 = (((fr + 16) << 3) + (g ^ (fr & 7))) << 3;
    int cK3 = (((fr + 16) << 3) + ((g + 4) ^ (fr & 7))) << 3;
    int cVg = (g ^ ((fr >> 1) & 3)) << 3;    // V read-chunk (row>>1 bits = fr>>1)

    auto HALF = [&](int base) {
        s16x8 Kf0 = *(const s16x8*)&kls[base + cK0];
        s16x8 Kf1 = *(const s16x8*)&kls[base + cK1];
        s16x8 Kf2 = *(const s16x8*)&kls[base + cK2];
        s16x8 Kf3 = *(const s16x8*)&kls[base + cK3];
        s16x8 Vf[4];
#pragma unroll
        for (int t4 = 0; t4 < 4; ++t4)
            Vf[t4] = *(const s16x8*)&vls[base + ((t4 * 16 + fr) << 5) + cVg];
        s16x8 pa[2];
#pragma unroll
        for (int s = 0; s < 2; ++s) {
            __builtin_amdgcn_s_setprio(1);
            f32x4 t0 = mfma16(Kf0, qf[s][0], zz);
            t0 = mfma16(Kf1, qf[s][1], t0);
            f32x4 t1 = mfma16(Kf2, qf[s][0], zz);
            t1 = mfma16(Kf3, qf[s][1], t1);
            __builtin_amdgcn_s_setprio(0);
            float p00 = EXP2(t0[0]), p01 = EXP2(t0[1]);
            float p02 = EXP2(t0[2]), p03 = EXP2(t0[3]);
            float p10 = EXP2(t1[0]), p11 = EXP2(t1[1]);
            float p12 = EXP2(t1[2]), p13 = EXP2(t1[3]);
            lsum[s] += (p00 + p01 + p02 + p03) + (p10 + p11 + p12 + p13);
            unsigned w0, w1, w2, w3;
            asm("v_cvt_pk_bf16_f32 %0, %1, %2" : "=v"(w0) : "v"(p00), "v"(p01));
            asm("v_cvt_pk_bf16_f32 %0, %1, %2" : "=v"(w1) : "v"(p02), "v"(p03));
            asm("v_cvt_pk_bf16_f32 %0, %1, %2" : "=v"(w2) : "v"(p10), "v"(p11));
            asm("v_cvt_pk_bf16_f32 %0, %1, %2" : "=v"(w3) : "v"(p12), "v"(p13));
            int e0 = __shfl((int)w0, srcA), e1 = __shfl((int)w1, srcA);
            int e2 = __shfl((int)w0, srcB), e3 = __shfl((int)w1, srcB);
            int f0 = __shfl((int)w2, srcA), f1 = __shfl((int)w3, srcA);
            int f2 = __shfl((int)w2, srcB), f3 = __shfl((int)w3, srcB);
            int4 wd;
            wd.x = glo ? e0 : f0;
            wd.y = glo ? e1 : f1;
            wd.z = glo ? e2 : f2;
            wd.w = glo ? e3 : f3;
            pa[s] = __builtin_bit_cast(s16x8, wd);
        }
        __builtin_amdgcn_s_setprio(1);
#pragma unroll
        for (int t4 = 0; t4 < 4; ++t4) {
            acc[0][t4] = mfma16(pa[0], Vf[t4], acc[0][t4]);
            acc[1][t4] = mfma16(pa[1], Vf[t4], acc[1][t4]);
        }
        __builtin_amdgcn_s_setprio(0);
    };

    for (int kb = 0; kb < 1024; kb += 64) {
        gld16(Kh + (size_t)(kb + half * 32 + krow) * 64 + kgc * 8, &kls[lbase]);
        gld16(Vh + (size_t)vdr * 1024 + kb + half * 32 + vgc * 8, &vls[lbase]);
        __syncthreads();   // drains vmcnt: both sub-tiles ready
        HALF(0);
        HALF(2048);
        __syncthreads();   // all reads done before next stage overwrites
    }

    float invv[2][4];
#pragma unroll
    for (int s = 0; s < 2; ++s) {
        float l = lsum[s];
        l += __shfl_xor(l, 16);
        l += __shfl_xor(l, 32);
        float inv = 1.0f / l;
#pragma unroll
        for (int r = 0; r < 4; ++r)
            invv[s][r] = __shfl(inv, ((lane >> 4) << 2) + r);
    }
#pragma unroll
    for (int s = 0; s < 2; ++s) {
        u16* ob = Op + (size_t)(b * 1024 + q0 + s * 16 + ((lane >> 4) << 2)) * 768 + h * 64 + fr;
#pragma unroll
        for (int t4 = 0; t4 < 4; ++t4)
#pragma unroll
            for (int r = 0; r < 4; ++r)
                ob[(size_t)r * 768 + t4 * 16] = f2bf(acc[s][t4][r] * invv[s][r]);
    }
}

// -----------------------------------------------------------------------------
extern "C" void kernel_launch(void* const* d_in, const int* in_sizes, int n_in,
                              void* d_out, int out_size, void* d_ws, size_t ws_size,
                              hipStream_t stream) {
    (void)in_sizes; (void)n_in; (void)out_size;
    const float* X    = (const float*)d_in[0];
    const float* Y    = (const float*)d_in[1];
    const float* l1xg = (const float*)d_in[2];
    const float* l1xb = (const float*)d_in[3];
    const float* l1yg = (const float*)d_in[4];
    const float* l1yb = (const float*)d_in[5];
    const float* Wq   = (const float*)d_in[6];
    const float* bq   = (const float*)d_in[7];
    const float* Wk   = (const float*)d_in[8];
    const float* bk   = (const float*)d_in[9];
    const float* Wv   = (const float*)d_in[10];
    const float* bv   = (const float*)d_in[11];
    const float* Wo   = (const float*)d_in[12];
    const float* bo   = (const float*)d_in[13];
    const float* Wqd  = (const float*)d_in[14];
    const float* bqd  = (const float*)d_in[15];
    const float* Wkd  = (const float*)d_in[16];
    const float* bkd  = (const float*)d_in[17];
    const float* Wvd  = (const float*)d_in[18];
    const float* bvd  = (const float*)d_in[19];
    const float* Wod  = (const float*)d_in[20];
    const float* bod  = (const float*)d_in[21];
    const float* w11  = (const float*)d_in[22];
    const float* w12  = (const float*)d_in[23];
    const float* w21  = (const float*)d_in[24];
    const float* w22  = (const float*)d_in[25];
    const float* l2xg = (const float*)d_in[26];
    const float* l2xb = (const float*)d_in[27];
    const float* l2yg = (const float*)d_in[28];
    const float* l2yb = (const float*)d_in[29];
    const float* W1   = (const float*)d_in[30];
    const float* b1   = (const float*)d_in[31];
    const float* W2   = (const float*)d_in[32];
    const float* b2   = (const float*)d_in[33];
    const float* W1d  = (const float*)d_in[34];
    const float* b1d  = (const float*)d_in[35];
    const float* W2d  = (const float*)d_in[36];
    const float* b2d  = (const float*)d_in[37];

    u16* ws = (u16*)d_ws;
    u16* qkvT = ws;
    u16* WoT  = qkvT + 6 * DDE;
    u16* W1T  = WoT + 2 * DDE;
    u16* W2T  = W1T + 2 * DFE;
    u16* xn   = W2T + 2 * DFE;   // 2E: xn,yn (also LN2 outs later)
    u16* Qx   = xn + 2 * EL;     // 6E: Qx,Kx,VTx,Qy,Ky,VTy ; h aliases (8E)
    u16* cs   = Qx + 6 * EL;     // 4E: csx,csy,ccx,ccy (also Vrow scratch)
    u16* x1   = cs + 4 * EL;     // 2E bf16: x1,y1
    u16* Kx = Qx + EL;
    u16* VTx = Qx + 2 * EL;
    u16* h = Qx;                 // MLP hidden: x at h, y at h+4E
    u16* y1 = x1 + EL;
    u16* wsEnd = x1 + 2 * EL;    // end of fixed layout
    u16* Vrow = cs;              // V row-major scratch (2E), dead before attn writes cs

    float* out_x = (float*)d_out;

    float* parts = (float*)wsEnd;
    size_t baseBytes = (size_t)(wsEnd - ws) * 2;
    size_t partBytes = 2 * EL * sizeof(float);
    int KS = 1;
    if (ws_size >= baseBytes + 4 * partBytes) KS = 4;
    else if (ws_size >= baseBytes + 2 * partBytes) KS = 2;

    dim3 tb(256);
    transpose8_k<<<dim3(12, 12, 8), tb, 0, stream>>>(Wq, Wk, Wv, Wqd, Wkd, Wvd, Wo, Wod, qkvT);
    transpose2_k<<<dim3(48, 12, 2), tb, 0, stream>>>(W1, W1d, W1T, DFE, 768, 3072);
    transpose2_k<<<dim3(12, 48, 2), tb, 0, stream>>>(W2, W2d, W2T, DFE, 3072, 768);
    ln_k<<<dim3(4096, 2), tb, 0, stream>>>(X, Y, l1xg, l1xb, l1yg, l1yb, xn);
    gemm_qkv_k<<<1152, tb, 0, stream>>>(xn, qkvT, bq, bk, bv, bqd, bkd, bvd,
                                        Qx, Kx, Vrow);
    vtrans_k<<<dim3(16, 48, 2), tb, 0, stream>>>(Vrow, VTx);
    // attn: 768 blocks x 512 threads = 2 pair x 48 bh x 8 qt, 2 cfgs per block
    attn_k<<<768, dim3(512), 0, stream>>>(Qx, Kx, VTx, Qx + 3 * EL, Qx + 4 * EL, Qx + 5 * EL,
                                          cs, cs + 2 * EL, cs + EL, cs + 3 * EL);
    int n8 = (int)(EL / 8);
    blend_k<<<dim3(1536, 1, 2), tb, 0, stream>>>(cs, cs + 2 * EL, w11, w12, w21, w22, n8);
    gemm_k<EPI_WO><<<384, tb, 0, stream>>>(
        cs, EL, WoT, DDE, bo, bod, X, Y, w11, w12, w21, w22, x1, EL,
        4096, 768, 768, 6, 1);
    lnb_k<<<dim3(4096, 2), tb, 0, stream>>>(x1, y1, l2xg, l2xb, l2yg, l2yb, xn);
    gemm_k<EPI_GELU><<<1536, tb, 0, stream>>>(
        xn, EL, W1T, DFE, b1, b1d, nullptr, nullptr, nullptr, nullptr, nullptr, nullptr,
        h, 4 * EL, 4096, 3072, 768, 24, 1);
    if (KS > 1) {
        gemm_k<EPI_PART><<<384 * KS, tb, 0, stream>>>(
            h, 4 * EL, W2T, DFE, nullptr, nullptr, nullptr, nullptr,
            nullptr, nullptr, nullptr, nullptr,
            parts, EL, 4096, 768, 3072, 6, KS);
        int n4 = (int)(2 * EL / 4);
        combine_k<<<(n4 + 255) / 256, tb, 0, stream>>>(parts, KS, x1, b2, b2d,
                                                       out_x, n4);
    } else {
        gemm_k<EPI_MLP2><<<384, tb, 0, stream>>>(
            h, 4 * EL, W2T, DFE, b2, b2d, x1, y1,
            nullptr, nullptr, nullptr, nullptr,
            out_x, EL, 4096, 768, 3072, 6, 1);
    }
}

// Round 22
// 423.840 us; speedup vs baseline: 1.0318x; 1.0290x over previous
//
#include <hip/hip_runtime.h>

typedef unsigned short u16;
typedef unsigned short u16x8 __attribute__((ext_vector_type(8)));
typedef short s16x8 __attribute__((ext_vector_type(8)));
typedef float f32x4 __attribute__((ext_vector_type(4)));

#define EL ((size_t)3145728)       // 4096*768
#define DDE ((size_t)589824)       // 768*768
#define DFE ((size_t)2359296)      // 768*3072

#if __has_builtin(__builtin_amdgcn_exp2f)
#define EXP2(x) __builtin_amdgcn_exp2f(x)
#else
#define EXP2(x) __expf((x) * 0.6931471805599453f)
#endif

__device__ __forceinline__ float b2f(u16 u) {
    return __builtin_bit_cast(float, (unsigned)u << 16);
}
__device__ __forceinline__ u16 f2bf(float f) {
    unsigned x = __builtin_bit_cast(unsigned, f);
    return (u16)((x + 0x7fffu + ((x >> 16) & 1u)) >> 16);
}
__device__ __forceinline__ float gelu_f(float x) {
    float t = x + 0.044715f * x * x * x;
    return x * __builtin_amdgcn_rcpf(1.0f + EXP2(-2.302207417f * t));
}
__device__ __forceinline__ f32x4 mfma16(s16x8 a, s16x8 b, f32x4 c) {
    return __builtin_amdgcn_mfma_f32_16x16x32_bf16(a, b, c, 0, 0, 0);
}
__device__ __forceinline__ void gld16(const u16* g, u16* l) {
    __builtin_amdgcn_global_load_lds((const __attribute__((address_space(1))) void*)g,
                                     (__attribute__((address_space(3))) void*)l,
                                     16, 0, 0);
}
// XCD panel-ownership map: 1D grid T (T%8==0, (T/8)%NN==0).
__device__ __forceinline__ void xcd_map(int NN, int& m, int& n, int& z, int& ks) {
    int p = blockIdx.x, T = gridDim.x;
    int ppx = T >> 3;
    int xcd = p & 7, l = p >> 3;
    int panel = l / NN;
    n = l - panel * NN;
    int gp = xcd * (ppx / NN) + panel;
    m = gp & 31;
    z = (gp >> 5) & 1;
    ks = gp >> 6;
}

// ------- transpose+cast, 8-batch (768x768 each): z selects src; dst+z*DDE ----
__global__ __launch_bounds__(256) void transpose8_k(const float* p0, const float* p1,
                                                    const float* p2, const float* p3,
                                                    const float* p4, const float* p5,
                                                    const float* p6, const float* p7,
                                                    u16* __restrict__ dst0) {
    int z = blockIdx.z;
    const float* in = z == 0 ? p0 : z == 1 ? p1 : z == 2 ? p2 : z == 3 ? p3
                    : z == 4 ? p4 : z == 5 ? p5 : z == 6 ? p6 : p7;
    u16* out = dst0 + (size_t)z * DDE;
    const int K = 768, N = 768;
    __shared__ u16 tile[64][72];
    int k0 = blockIdx.y << 6, n0 = blockIdx.x << 6;
    int tid = threadIdx.x;
    int r = tid >> 2, c = (tid & 3) << 4;
    const float* ip = in + (size_t)(k0 + r) * N + n0 + c;
#pragma unroll
    for (int q = 0; q < 4; ++q) {
        f32x4 v = *(const f32x4*)(ip + 4 * q);
#pragma unroll
        for (int e = 0; e < 4; ++e) tile[r][c + 4 * q + e] = f2bf(v[e]);
    }
    __syncthreads();
    u16x8 o0, o1;
#pragma unroll
    for (int e = 0; e < 8; ++e) { o0[e] = tile[c + e][r]; o1[e] = tile[c + 8 + e][r]; }
    u16* op = out + (size_t)(n0 + r) * K + k0 + c;
    *(u16x8*)op = o0;
    *(u16x8*)(op + 8) = o1;
}

// ------- transpose+cast, 2-batch: in [K][N] f32 -> out bf16 [N][K] -----------
__global__ __launch_bounds__(256) void transpose2_k(const float* pa, const float* pb,
                                                    u16* __restrict__ dst0, size_t dsz,
                                                    int K, int N) {
    int z = blockIdx.z;
    const float* in = z ? pb : pa;
    u16* out = dst0 + (size_t)z * dsz;
    __shared__ u16 tile[64][72];
    int k0 = blockIdx.y << 6, n0 = blockIdx.x << 6;
    int tid = threadIdx.x;
    int r = tid >> 2, c = (tid & 3) << 4;
    const float* ip = in + (size_t)(k0 + r) * N + n0 + c;
#pragma unroll
    for (int q = 0; q < 4; ++q) {
        f32x4 v = *(const f32x4*)(ip + 4 * q);
#pragma unroll
        for (int e = 0; e < 4; ++e) tile[r][c + 4 * q + e] = f2bf(v[e]);
    }
    __syncthreads();
    u16x8 o0, o1;
#pragma unroll
    for (int e = 0; e < 8; ++e) { o0[e] = tile[c + e][r]; o1[e] = tile[c + 8 + e][r]; }
    u16* op = out + (size_t)(n0 + r) * K + k0 + c;
    *(u16x8*)op = o0;
    *(u16x8*)(op + 8) = o1;
}

// ------- V row-major [B,H,S,64] -> VT [B,H,64,S]; grid (16 st, 48 bh, 2 z) ---
__global__ __launch_bounds__(256) void vtrans_k(const u16* __restrict__ Vrow,
                                                u16* __restrict__ VT0) {
    int st = blockIdx.x, bh = blockIdx.y, z = blockIdx.z;
    const u16* src = Vrow + (size_t)z * EL + ((size_t)bh << 16) + (size_t)st * 64 * 64;
    u16* dst = VT0 + (size_t)z * 3 * EL + ((size_t)bh << 16) + st * 64;
    __shared__ u16 tile[64][72];
    int tid = threadIdx.x;
    int r = tid >> 2, c = (tid & 3) << 4;
    const u16* ip = src + (size_t)r * 64 + c;
    u16x8 a = *(const u16x8*)ip;
    u16x8 b = *(const u16x8*)(ip + 8);
#pragma unroll
    for (int e = 0; e < 8; ++e) { tile[r][c + e] = a[e]; tile[r][c + 8 + e] = b[e]; }
    __syncthreads();
    u16x8 o0, o1;
#pragma unroll
    for (int e = 0; e < 8; ++e) { o0[e] = tile[c + e][r]; o1[e] = tile[c + 8 + e][r]; }
    u16* op = dst + (size_t)r * 1024 + c;
    *(u16x8*)op = o0;
    *(u16x8*)(op + 8) = o1;
}

// ------- LayerNorm D=768, f32 in, bf16 out; 2-batch via blockIdx.y ----------
__global__ __launch_bounds__(256) void ln_k(const float* __restrict__ inX,
                                            const float* __restrict__ inY,
                                            const float* gX, const float* bX,
                                            const float* gY, const float* bY,
                                            u16* __restrict__ out0) {
    int z = blockIdx.y;
    const float* in = z ? inY : inX;
    const float* g = z ? gY : gX;
    const float* be = z ? bY : bX;
    u16* out = out0 + (size_t)z * EL;
    int row = blockIdx.x, tid = threadIdx.x;
    const float* p = in + (size_t)row * 768;
    float v0 = p[tid], v1 = p[tid + 256], v2 = p[tid + 512];
    float s = v0 + v1 + v2;
    float q = v0 * v0 + v1 * v1 + v2 * v2;
#pragma unroll
    for (int m = 1; m < 64; m <<= 1) { s += __shfl_xor(s, m); q += __shfl_xor(q, m); }
    __shared__ float red[8];
    int w = tid >> 6, lane = tid & 63;
    if (lane == 0) { red[w] = s; red[4 + w] = q; }
    __syncthreads();
    s = red[0] + red[1] + red[2] + red[3];
    q = red[4] + red[5] + red[6] + red[7];
    float mean = s * (1.0f / 768.0f);
    float var = q * (1.0f / 768.0f) - mean * mean;
    float rstd = rsqrtf(var + 1e-6f);
    u16* o = out + (size_t)row * 768;
    o[tid]       = f2bf((v0 - mean) * rstd * g[tid]       + be[tid]);
    o[tid + 256] = f2bf((v1 - mean) * rstd * g[tid + 256] + be[tid + 256]);
    o[tid + 512] = f2bf((v2 - mean) * rstd * g[tid + 512] + be[tid + 512]);
}

// ------- LayerNorm D=768, bf16 in, bf16 out (LN2 on x1/y1) ------------------
__global__ __launch_bounds__(256) void lnb_k(const u16* __restrict__ inX,
                                             const u16* __restrict__ inY,
                                             const float* gX, const float* bX,
                                             const float* gY, const float* bY,
                                             u16* __restrict__ out0) {
    int z = blockIdx.y;
    const u16* in = z ? inY : inX;
    const float* g = z ? gY : gX;
    const float* be = z ? bY : bX;
    u16* out = out0 + (size_t)z * EL;
    int row = blockIdx.x, tid = threadIdx.x;
    const u16* p = in + (size_t)row * 768;
    float v0 = b2f(p[tid]), v1 = b2f(p[tid + 256]), v2 = b2f(p[tid + 512]);
    float s = v0 + v1 + v2;
    float q = v0 * v0 + v1 * v1 + v2 * v2;
#pragma unroll
    for (int m = 1; m < 64; m <<= 1) { s += __shfl_xor(s, m); q += __shfl_xor(q, m); }
    __shared__ float red[8];
    int w = tid >> 6, lane = tid & 63;
    if (lane == 0) { red[w] = s; red[4 + w] = q; }
    __syncthreads();
    s = red[0] + red[1] + red[2] + red[3];
    q = red[4] + red[5] + red[6] + red[7];
    float mean = s * (1.0f / 768.0f);
    float var = q * (1.0f / 768.0f) - mean * mean;
    float rstd = rsqrtf(var + 1e-6f);
    u16* o = out + (size_t)row * 768;
    o[tid]       = f2bf((v0 - mean) * rstd * g[tid]       + be[tid]);
    o[tid + 256] = f2bf((v1 - mean) * rstd * g[tid + 256] + be[tid + 256]);
    o[tid + 512] = f2bf((v2 - mean) * rstd * g[tid + 512] + be[tid + 512]);
}

// ------- blend, 2-batch: a[z] = w1[z]*a[z] + w2[z]*b[z] ----------------------
__global__ __launch_bounds__(256) void blend_k(u16* __restrict__ a0,
                                               const u16* __restrict__ b0,
                                               const float* w11, const float* w12,
                                               const float* w21, const float* w22,
                                               int n8) {
    int z = blockIdx.z;
    u16* a = a0 + (size_t)z * EL;
    const u16* b = b0 + (size_t)z * EL;
    float wa = z ? *w21 : *w11, wb = z ? *w22 : *w12;
    for (int i = blockIdx.x * blockDim.x + threadIdx.x; i < n8;
         i += gridDim.x * blockDim.x) {
        u16x8 va = ((const u16x8*)a)[i];
        u16x8 vb = ((const u16x8*)b)[i];
        u16x8 r;
#pragma unroll
        for (int e = 0; e < 8; ++e) r[e] = f2bf(wa * b2f(va[e]) + wb * b2f(vb[e]));
        ((u16x8*)a)[i] = r;
    }
}

// ------- split-K combine: out = sum(parts) + b2[n] + x1(bf16) ----------------
__global__ __launch_bounds__(256) void combine_k(const float* __restrict__ parts,
                                                 int KS,
                                                 const u16* __restrict__ x1b,
                                                 const float* __restrict__ b2X,
                                                 const float* __restrict__ b2Y,
                                                 float* __restrict__ out, int n4tot) {
    int i = blockIdx.x * 256 + threadIdx.x;
    if (i >= n4tot) return;
    size_t e = (size_t)i * 4;
    f32x4 s = ((const f32x4*)parts)[i];
    for (int k = 1; k < KS; ++k)
        s += ((const f32x4*)(parts + (size_t)k * 2 * EL))[i];
    const float* bb = (e < EL) ? b2X : b2Y;
    int n = (int)(e % 768);
    ushort4 xv = ((const ushort4*)x1b)[i];
    f32x4 r;
    r[0] = s[0] + bb[n]     + b2f(xv.x);
    r[1] = s[1] + bb[n + 1] + b2f(xv.y);
    r[2] = s[2] + bb[n + 2] + b2f(xv.z);
    r[3] = s[3] + bb[n + 3] + b2f(xv.w);
    ((f32x4*)out)[i] = r;
}

#define EPI_GELU 3
#define EPI_WO 4     // resid f32 (X/Y), bias*(wa+wb), out bf16 (x1/y1)
#define EPI_MLP2 5   // resid bf16 (x1/y1), +bias, out f32 (d_out)
#define EPI_PART 6   // split-K partial: plain f32 store to parts[ks][z]

// ------- GEMM BM=128 BN=128 BK=32, 1D grid + xcd_map, optional split-K -------
template <int EPI>
__global__ __launch_bounds__(256) void gemm_k(
    const u16* __restrict__ A0, size_t Asz,
    const u16* __restrict__ B0, size_t Bsz,
    const float* __restrict__ bias0, const float* __restrict__ bias1,
    const void* __restrict__ r0, const void* __restrict__ r1,
    const float* s1a, const float* s1b, const float* s2a, const float* s2b,
    void* __restrict__ C0, size_t Csz,
    int M, int N, int K, int NN, int KS) {
    int m_, n_, z, ks;
    xcd_map(NN, m_, n_, z, ks);
    const int Kloc = K / KS;
    const u16* A = A0 + z * Asz;
    const u16* BT = B0 + z * Bsz;
    const float* bias = z ? bias1 : bias0;
    const float* residf = (const float*)(z ? r1 : r0);
    const u16* residb = (const u16*)(z ? r1 : r0);
    u16* Cb = (u16*)C0 + z * Csz;
    float* Cf = (float*)C0 + ((size_t)ks * 2 + z) * Csz;
    __shared__ u16 lA[2][4096];
    __shared__ u16 lB[2][4096];
    int tid = threadIdx.x;
    int bm0 = m_ << 7, bn0 = n_ << 7;
    int lane = tid & 63, wid = tid >> 6;
    int fr = lane & 15, g = lane >> 4;
    int wm = wid >> 1, wn = wid & 1;
    const u16* srcA0 = A + (size_t)(bm0 + (tid & 127)) * K + ks * Kloc + ((tid >> 7) << 3);
    const u16* srcA1 = srcA0 + 16;
    const u16* srcB0 = BT + (size_t)(bn0 + (tid & 127)) * K + ks * Kloc + ((tid >> 7) << 3);
    const u16* srcB1 = srcB0 + 16;
    auto STAGE = [&](int buf, int k0) {
        gld16(srcA0 + k0, &lA[buf][0] + tid * 8);
        gld16(srcA1 + k0, &lA[buf][0] + 2048 + tid * 8);
        gld16(srcB0 + k0, &lB[buf][0] + tid * 8);
        gld16(srcB1 + k0, &lB[buf][0] + 2048 + tid * 8);
    };
    f32x4 acc[4][4] = {};
    STAGE(0, 0);
    __syncthreads();
    int cur = 0;
    for (int k0 = 0; k0 < Kloc; k0 += 32) {
        if (k0 + 32 < Kloc) STAGE(cur ^ 1, k0 + 32);
        s16x8 af[4], bf[4];
#pragma unroll
        for (int i = 0; i < 4; ++i)
            af[i] = *(const s16x8*)&lA[cur][(g * 128 + wm * 64 + i * 16 + fr) * 8];
#pragma unroll
        for (int j = 0; j < 4; ++j)
            bf[j] = *(const s16x8*)&lB[cur][(g * 128 + wn * 64 + j * 16 + fr) * 8];
#pragma unroll
        for (int i = 0; i < 4; ++i)
#pragma unroll
            for (int j = 0; j < 4; ++j)
                acc[i][j] = mfma16(af[i], bf[j], acc[i][j]);
        __syncthreads();
        cur ^= 1;
    }
    float bscale = 1.0f;
    if (EPI == EPI_WO) bscale = z ? (s2a[0] + s2b[0]) : (s1a[0] + s1b[0]);
#pragma unroll
    for (int j = 0; j < 4; ++j) {
        int n = bn0 + wn * 64 + j * 16 + fr;
        float bv = 0.0f;
        if (EPI != EPI_PART) bv = bias[n] * bscale;
#pragma unroll
        for (int i = 0; i < 4; ++i) {
#pragma unroll
            for (int r = 0; r < 4; ++r) {
                int m = bm0 + wm * 64 + i * 16 + (g << 2) + r;
                size_t idx = (size_t)m * N + n;
                float v = acc[i][j][r] + bv;
                if (EPI == EPI_GELU) {
                    Cb[idx] = f2bf(gelu_f(v));
                } else if (EPI == EPI_WO) {
                    Cb[idx] = f2bf(v + residf[idx]);
                } else if (EPI == EPI_MLP2) {
                    Cf[idx] = v + b2f(residb[idx]);
                } else {
                    Cf[idx] = v;   // EPI_PART: partial, combined later
                }
            }
        }
    }
}

// ------- fused QKV GEMM. Q pre-scaled by 0.125*log2(e). ----------------------
// ALL segments store row-major head-split [B,H,S,64]; V transposed afterwards.
__global__ __launch_bounds__(256) void gemm_qkv_k(const u16* __restrict__ A0,
                                                  const u16* __restrict__ B0,
                                                  const float* bq, const float* bk,
                                                  const float* bv, const float* bqd,
                                                  const float* bkd, const float* bvd,
                                                  u16* __restrict__ Qd,
                                                  u16* __restrict__ Kd,
                                                  u16* __restrict__ Vd) {
    const int K = 768;
    int m_, n_, z, ks_;
    xcd_map(18, m_, n_, z, ks_);
    const u16* A = A0 + z * EL;
    const u16* BT = B0 + z * 3 * DDE;
    __shared__ u16 lA[2][4096];
    __shared__ u16 lB[2][4096];
    int tid = threadIdx.x;
    int bm0 = m_ << 7, bn0 = n_ << 7;
    int lane = tid & 63, wid = tid >> 6, wm = wid >> 1, wn = wid & 1;
    int fr = lane & 15, g = lane >> 4;
    const u16* srcA0 = A + (size_t)(bm0 + (tid & 127)) * K + ((tid >> 7) << 3);
    const u16* srcA1 = srcA0 + 16;
    const u16* srcB0 = BT + (size_t)(bn0 + (tid & 127)) * K + ((tid >> 7) << 3);
    const u16* srcB1 = srcB0 + 16;
    auto STAGE = [&](int buf, int k0) {
        gld16(srcA0 + k0, &lA[buf][0] + tid * 8);
        gld16(srcA1 + k0, &lA[buf][0] + 2048 + tid * 8);
        gld16(srcB0 + k0, &lB[buf][0] + tid * 8);
        gld16(srcB1 + k0, &lB[buf][0] + 2048 + tid * 8);
    };
    f32x4 acc[4][4] = {};
    STAGE(0, 0);
    __syncthreads();
    int cur = 0;
    for (int k0 = 0; k0 < K; k0 += 32) {
        if (k0 + 32 < K) STAGE(cur ^ 1, k0 + 32);
        s16x8 af[4], bf[4];
#pragma unroll
        for (int i = 0; i < 4; ++i)
            af[i] = *(const s16x8*)&lA[cur][(g * 128 + wm * 64 + i * 16 + fr) * 8];
#pragma unroll
        for (int j = 0; j < 4; ++j)
            bf[j] = *(const s16x8*)&lB[cur][(g * 128 + wn * 64 + j * 16 + fr) * 8];
#pragma unroll
        for (int i = 0; i < 4; ++i)
#pragma unroll
            for (int j = 0; j < 4; ++j)
                acc[i][j] = mfma16(af[i], bf[j], acc[i][j]);
        __syncthreads();
        cur ^= 1;
    }
    int seg = bn0 / 768;
    const float* bp = seg == 0 ? (z ? bqd : bq) : seg == 1 ? (z ? bkd : bk) : (z ? bvd : bv);
    u16* out;
    size_t zoff;
    if (seg == 0)      { out = Qd; zoff = (size_t)z * 3 * EL; }
    else if (seg == 1) { out = Kd; zoff = (size_t)z * 3 * EL; }
    else               { out = Vd; zoff = (size_t)z * EL; }
    int nbase = bn0 - seg * 768;
    const float qs = (seg == 0) ? 0.180336880f : 1.0f;  // 0.125 * log2(e)
#pragma unroll
    for (int j = 0; j < 4; ++j) {
        int nn = nbase + wn * 64 + j * 16 + fr;
        float bvl = bp[nn];
        int hh = nn >> 6, hd = nn & 63;
#pragma unroll
        for (int i = 0; i < 4; ++i) {
#pragma unroll
            for (int r = 0; r < 4; ++r) {
                int m = bm0 + wm * 64 + i * 16 + (g << 2) + r;
                int bb = m >> 10, ss = m & 1023;
                size_t o = zoff + (((size_t)(bb * 12 + hh)) << 16) + ((size_t)ss << 6) + hd;
                out[o] = f2bf((acc[i][j][r] + bvl) * qs);
            }
        }
    }
}

// ------- fused attention v8: v4 (256 thr, KVBLK=64) + V-tile XOR swizzle -----
// LDS-staged K/V shared by 4 waves; swapped-QK^T register-shuffle P path.
// V chunk permutation c' = c ^ ((row>>1)&3), applied on the global SOURCE
// during staging (LDS dest linear) and on the read address; kills the 8-way
// V-read bank conflict (verified in R21: conflicts -3.1M).
__global__ __launch_bounds__(256) void attn_k(const u16* __restrict__ Qx,
                                              const u16* __restrict__ Kx,
                                              const u16* __restrict__ VTx,
                                              const u16* __restrict__ Qy,
                                              const u16* __restrict__ Ky,
                                              const u16* __restrict__ VTy,
                                              u16* __restrict__ csx,
                                              u16* __restrict__ ccx,
                                              u16* __restrict__ csy,
                                              u16* __restrict__ ccy) {
    int p = blockIdx.x;
    int lg = (p & 7) * 192 + (p >> 3);       // contiguous logical ids per XCD
    int sg = lg >> 4, wi = lg & 15;          // supergroup = K/V-sharing pair
    int qt = wi & 7, sub = wi >> 3;
    int pairi = sg / 48, bh = sg % 48;
    int cfg = pairi == 0 ? (sub ? 3 : 0) : (sub ? 2 : 1);
    const u16 *Qp, *Kp, *Vp;
    u16* Op;
    if (cfg == 0)      { Qp = Qx; Kp = Kx; Vp = VTx; Op = csx; }
    else if (cfg == 1) { Qp = Qy; Kp = Ky; Vp = VTy; Op = csy; }
    else if (cfg == 2) { Qp = Qx; Kp = Ky; Vp = VTy; Op = ccx; }
    else               { Qp = Qy; Kp = Kx; Vp = VTx; Op = ccy; }
    const u16* Qh = Qp + ((size_t)bh << 16);
    const u16* Kh = Kp + ((size_t)bh << 16);
    const u16* Vh = Vp + ((size_t)bh << 16);
    int b = bh / 12, h = bh % 12;
    int tid = threadIdx.x, lane = tid & 63, w = tid >> 6;
    int q0 = qt * 128 + w * 32;
    int fr = lane & 15, ko = (lane >> 4) << 3, g = lane >> 4;
    bool glo = lane < 32;
    int srcA = fr + ((lane & 16) << 1);
    int srcB = srcA + 16;

    __shared__ u16 kls[4096];   // 2 x (32 keys x 64 d), chunks XOR-swizzled
    __shared__ u16 vls[4096];   // 2 x (64 d x 32 keys), chunks XOR-swizzled

    s16x8 qf[2][2];
#pragma unroll
    for (int s = 0; s < 2; ++s) {
        const u16* qp = Qh + (size_t)(q0 + s * 16 + fr) * 64 + ko;
        qf[s][0] = *(const s16x8*)qp;
        qf[s][1] = *(const s16x8*)(qp + 32);
    }

    f32x4 acc[2][4] = {};
    float lsum[2] = {0.f, 0.f};
    f32x4 zz = {0.f, 0.f, 0.f, 0.f};

    int krow = tid >> 3, kpc = tid & 7;
    int kgc = kpc ^ (krow & 7);              // K source-chunk swizzle
    int vdr = tid >> 2, vpv = tid & 3;
    int vgc = vpv ^ ((vdr >> 1) & 3);        // V source-chunk swizzle
    int cK0 = ((fr << 3) + (g ^ (fr & 7))) << 3;
    int cK1 = ((fr << 3) + ((g + 4) ^ (fr & 7))) << 3;
    int cK2 = (((fr + 16) << 3) + (g ^ (fr & 7))) << 3;
    int cK3 = (((fr + 16) << 3) + ((g + 4) ^ (fr & 7))) << 3;
    int cVg = (g ^ ((fr >> 1) & 3)) << 3;    // V read-chunk

    auto HALF = [&](int base) {
        s16x8 Kf0 = *(const s16x8*)&kls[base + cK0];
        s16x8 Kf1 = *(const s16x8*)&kls[base + cK1];
        s16x8 Kf2 = *(const s16x8*)&kls[base + cK2];
        s16x8 Kf3 = *(const s16x8*)&kls[base + cK3];
        s16x8 Vf[4];
#pragma unroll
        for (int t4 = 0; t4 < 4; ++t4)
            Vf[t4] = *(const s16x8*)&vls[base + ((t4 * 16 + fr) << 5) + cVg];
        s16x8 pa[2];
#pragma unroll
        for (int s = 0; s < 2; ++s) {
            __builtin_amdgcn_s_setprio(1);
            f32x4 t0 = mfma16(Kf0, qf[s][0], zz);
            t0 = mfma16(Kf1, qf[s][1], t0);
            f32x4 t1 = mfma16(Kf2, qf[s][0], zz);
            t1 = mfma16(Kf3, qf[s][1], t1);
            __builtin_amdgcn_s_setprio(0);
            float p00 = EXP2(t0[0]), p01 = EXP2(t0[1]);
            float p02 = EXP2(t0[2]), p03 = EXP2(t0[3]);
            float p10 = EXP2(t1[0]), p11 = EXP2(t1[1]);
            float p12 = EXP2(t1[2]), p13 = EXP2(t1[3]);
            lsum[s] += (p00 + p01 + p02 + p03) + (p10 + p11 + p12 + p13);
            unsigned w0, w1, w2, w3;
            asm("v_cvt_pk_bf16_f32 %0, %1, %2" : "=v"(w0) : "v"(p00), "v"(p01));
            asm("v_cvt_pk_bf16_f32 %0, %1, %2" : "=v"(w1) : "v"(p02), "v"(p03));
            asm("v_cvt_pk_bf16_f32 %0, %1, %2" : "=v"(w2) : "v"(p10), "v"(p11));
            asm("v_cvt_pk_bf16_f32 %0, %1, %2" : "=v"(w3) : "v"(p12), "v"(p13));
            int e0 = __shfl((int)w0, srcA), e1 = __shfl((int)w1, srcA);
            int e2 = __shfl((int)w0, srcB), e3 = __shfl((int)w1, srcB);
            int f0 = __shfl((int)w2, srcA), f1 = __shfl((int)w3, srcA);
            int f2 = __shfl((int)w2, srcB), f3 = __shfl((int)w3, srcB);
            int4 wd;
            wd.x = glo ? e0 : f0;
            wd.y = glo ? e1 : f1;
            wd.z = glo ? e2 : f2;
            wd.w = glo ? e3 : f3;
            pa[s] = __builtin_bit_cast(s16x8, wd);
        }
        __builtin_amdgcn_s_setprio(1);
#pragma unroll
        for (int t4 = 0; t4 < 4; ++t4) {
            acc[0][t4] = mfma16(pa[0], Vf[t4], acc[0][t4]);
            acc[1][t4] = mfma16(pa[1], Vf[t4], acc[1][t4]);
        }
        __builtin_amdgcn_s_setprio(0);
    };

    for (int kb = 0; kb < 1024; kb += 64) {
        gld16(Kh + (size_t)(kb + krow) * 64 + kgc * 8, &kls[tid * 8]);
        gld16(Kh + (size_t)(kb + 32 + krow) * 64 + kgc * 8, &kls[2048 + tid * 8]);
        gld16(Vh + (size_t)vdr * 1024 + kb + vgc * 8, &vls[tid * 8]);
        gld16(Vh + (size_t)vdr * 1024 + kb + 32 + vgc * 8, &vls[2048 + tid * 8]);
        __syncthreads();   // drains vmcnt: both sub-tiles ready
        HALF(0);
        HALF(2048);
        __syncthreads();   // all reads done before next stage overwrites
    }

    float invv[2][4];
#pragma unroll
    for (int s = 0; s < 2; ++s) {
        float l = lsum[s];
        l += __shfl_xor(l, 16);
        l += __shfl_xor(l, 32);
        float inv = 1.0f / l;
#pragma unroll
        for (int r = 0; r < 4; ++r)
            invv[s][r] = __shfl(inv, ((lane >> 4) << 2) + r);
    }
#pragma unroll
    for (int s = 0; s < 2; ++s) {
        u16* ob = Op + (size_t)(b * 1024 + q0 + s * 16 + ((lane >> 4) << 2)) * 768 + h * 64 + fr;
#pragma unroll
        for (int t4 = 0; t4 < 4; ++t4)
#pragma unroll
            for (int r = 0; r < 4; ++r)
                ob[(size_t)r * 768 + t4 * 16] = f2bf(acc[s][t4][r] * invv[s][r]);
    }
}

// -----------------------------------------------------------------------------
extern "C" void kernel_launch(void* const* d_in, const int* in_sizes, int n_in,
                              void* d_out, int out_size, void* d_ws, size_t ws_size,
                              hipStream_t stream) {
    (void)in_sizes; (void)n_in; (void)out_size;
    const float* X    = (const float*)d_in[0];
    const float* Y    = (const float*)d_in[1];
    const float* l1xg = (const float*)d_in[2];
    const float* l1xb = (const float*)d_in[3];
    const float* l1yg = (const float*)d_in[4];
    const float* l1yb = (const float*)d_in[5];
    const float* Wq   = (const float*)d_in[6];
    const float* bq   = (const float*)d_in[7];
    const float* Wk   = (const float*)d_in[8];
    const float* bk   = (const float*)d_in[9];
    const float* Wv   = (const float*)d_in[10];
    const float* bv   = (const float*)d_in[11];
    const float* Wo   = (const float*)d_in[12];
    const float* bo   = (const float*)d_in[13];
    const float* Wqd  = (const float*)d_in[14];
    const float* bqd  = (const float*)d_in[15];
    const float* Wkd  = (const float*)d_in[16];
    const float* bkd  = (const float*)d_in[17];
    const float* Wvd  = (const float*)d_in[18];
    const float* bvd  = (const float*)d_in[19];
    const float* Wod  = (const float*)d_in[20];
    const float* bod  = (const float*)d_in[21];
    const float* w11  = (const float*)d_in[22];
    const float* w12  = (const float*)d_in[23];
    const float* w21  = (const float*)d_in[24];
    const float* w22  = (const float*)d_in[25];
    const float* l2xg = (const float*)d_in[26];
    const float* l2xb = (const float*)d_in[27];
    const float* l2yg = (const float*)d_in[28];
    const float* l2yb = (const float*)d_in[29];
    const float* W1   = (const float*)d_in[30];
    const float* b1   = (const float*)d_in[31];
    const float* W2   = (const float*)d_in[32];
    const float* b2   = (const float*)d_in[33];
    const float* W1d  = (const float*)d_in[34];
    const float* b1d  = (const float*)d_in[35];
    const float* W2d  = (const float*)d_in[36];
    const float* b2d  = (const float*)d_in[37];

    u16* ws = (u16*)d_ws;
    u16* qkvT = ws;
    u16* WoT  = qkvT + 6 * DDE;
    u16* W1T  = WoT + 2 * DDE;
    u16* W2T  = W1T + 2 * DFE;
    u16* xn   = W2T + 2 * DFE;   // 2E: xn,yn (also LN2 outs later)
    u16* Qx   = xn + 2 * EL;     // 6E: Qx,Kx,VTx,Qy,Ky,VTy ; h aliases (8E)
    u16* cs   = Qx + 6 * EL;     // 4E: csx,csy,ccx,ccy (also Vrow scratch)
    u16* x1   = cs + 4 * EL;     // 2E bf16: x1,y1
    u16* Kx = Qx + EL;
    u16* VTx = Qx + 2 * EL;
    u16* h = Qx;                 // MLP hidden: x at h, y at h+4E
    u16* y1 = x1 + EL;
    u16* wsEnd = x1 + 2 * EL;    // end of fixed layout
    u16* Vrow = cs;              // V row-major scratch (2E), dead before attn writes cs

    float* out_x = (float*)d_out;

    float* parts = (float*)wsEnd;
    size_t baseBytes = (size_t)(wsEnd - ws) * 2;
    size_t partBytes = 2 * EL * sizeof(float);
    int KS = 1;
    if (ws_size >= baseBytes + 4 * partBytes) KS = 4;
    else if (ws_size >= baseBytes + 2 * partBytes) KS = 2;

    dim3 tb(256);
    transpose8_k<<<dim3(12, 12, 8), tb, 0, stream>>>(Wq, Wk, Wv, Wqd, Wkd, Wvd, Wo, Wod, qkvT);
    transpose2_k<<<dim3(48, 12, 2), tb, 0, stream>>>(W1, W1d, W1T, DFE, 768, 3072);
    transpose2_k<<<dim3(12, 48, 2), tb, 0, stream>>>(W2, W2d, W2T, DFE, 3072, 768);
    ln_k<<<dim3(4096, 2), tb, 0, stream>>>(X, Y, l1xg, l1xb, l1yg, l1yb, xn);
    gemm_qkv_k<<<1152, tb, 0, stream>>>(xn, qkvT, bq, bk, bv, bqd, bkd, bvd,
                                        Qx, Kx, Vrow);
    vtrans_k<<<dim3(16, 48, 2), tb, 0, stream>>>(Vrow, VTx);
    attn_k<<<4 * 48 * 8, tb, 0, stream>>>(Qx, Kx, VTx, Qx + 3 * EL, Qx + 4 * EL, Qx + 5 * EL,
                                          cs, cs + 2 * EL, cs + EL, cs + 3 * EL);
    int n8 = (int)(EL / 8);
    blend_k<<<dim3(1536, 1, 2), tb, 0, stream>>>(cs, cs + 2 * EL, w11, w12, w21, w22, n8);
    gemm_k<EPI_WO><<<384, tb, 0, stream>>>(
        cs, EL, WoT, DDE, bo, bod, X, Y, w11, w12, w21, w22, x1, EL,
        4096, 768, 768, 6, 1);
    lnb_k<<<dim3(4096, 2), tb, 0, stream>>>(x1, y1, l2xg, l2xb, l2yg, l2yb, xn);
    gemm_k<EPI_GELU><<<1536, tb, 0, stream>>>(
        xn, EL, W1T, DFE, b1, b1d, nullptr, nullptr, nullptr, nullptr, nullptr, nullptr,
        h, 4 * EL, 4096, 3072, 768, 24, 1);
    if (KS > 1) {
        gemm_k<EPI_PART><<<384 * KS, tb, 0, stream>>>(
            h, 4 * EL, W2T, DFE, nullptr, nullptr, nullptr, nullptr,
            nullptr, nullptr, nullptr, nullptr,
            parts, EL, 4096, 768, 3072, 6, KS);
        int n4 = (int)(2 * EL / 4);
        combine_k<<<(n4 + 255) / 256, tb, 0, stream>>>(parts, KS, x1, b2, b2d,
                                                       out_x, n4);
    } else {
        gemm_k<EPI_MLP2><<<384, tb, 0, stream>>>(
            h, 4 * EL, W2T, DFE, b2, b2d, x1, y1,
            nullptr, nullptr, nullptr, nullptr,
            out_x, EL, 4096, 768, 3072, 6, 1);
    }
}

// Round 23
// 423.071 us; speedup vs baseline: 1.0337x; 1.0018x over previous
//
#include <hip/hip_runtime.h>

typedef unsigned short u16;
typedef unsigned short u16x8 __attribute__((ext_vector_type(8)));
typedef short s16x8 __attribute__((ext_vector_type(8)));
typedef float f32x4 __attribute__((ext_vector_type(4)));

#define EL ((size_t)3145728)       // 4096*768
#define DDE ((size_t)589824)       // 768*768
#define DFE ((size_t)2359296)      // 768*3072

#if __has_builtin(__builtin_amdgcn_exp2f)
#define EXP2(x) __builtin_amdgcn_exp2f(x)
#else
#define EXP2(x) __expf((x) * 0.6931471805599453f)
#endif

__device__ __forceinline__ float b2f(u16 u) {
    return __builtin_bit_cast(float, (unsigned)u << 16);
}
__device__ __forceinline__ u16 f2bf(float f) {
    unsigned x = __builtin_bit_cast(unsigned, f);
    return (u16)((x + 0x7fffu + ((x >> 16) & 1u)) >> 16);
}
__device__ __forceinline__ float gelu_f(float x) {
    float t = x + 0.044715f * x * x * x;
    return x * __builtin_amdgcn_rcpf(1.0f + EXP2(-2.302207417f * t));
}
__device__ __forceinline__ f32x4 mfma16(s16x8 a, s16x8 b, f32x4 c) {
    return __builtin_amdgcn_mfma_f32_16x16x32_bf16(a, b, c, 0, 0, 0);
}
__device__ __forceinline__ void gld16(const u16* g, u16* l) {
    __builtin_amdgcn_global_load_lds((const __attribute__((address_space(1))) void*)g,
                                     (__attribute__((address_space(3))) void*)l,
                                     16, 0, 0);
}
// XCD panel-ownership map: 1D grid T (T%8==0, (T/8)%NN==0).
__device__ __forceinline__ void xcd_map(int NN, int& m, int& n, int& z, int& ks) {
    int p = blockIdx.x, T = gridDim.x;
    int ppx = T >> 3;
    int xcd = p & 7, l = p >> 3;
    int panel = l / NN;
    n = l - panel * NN;
    int gp = xcd * (ppx / NN) + panel;
    m = gp & 31;
    z = (gp >> 5) & 1;
    ks = gp >> 6;
}

// ------- transpose+cast, 8-batch (768x768 each): z selects src; dst+z*DDE ----
__global__ __launch_bounds__(256) void transpose8_k(const float* p0, const float* p1,
                                                    const float* p2, const float* p3,
                                                    const float* p4, const float* p5,
                                                    const float* p6, const float* p7,
                                                    u16* __restrict__ dst0) {
    int z = blockIdx.z;
    const float* in = z == 0 ? p0 : z == 1 ? p1 : z == 2 ? p2 : z == 3 ? p3
                    : z == 4 ? p4 : z == 5 ? p5 : z == 6 ? p6 : p7;
    u16* out = dst0 + (size_t)z * DDE;
    const int K = 768, N = 768;
    __shared__ u16 tile[64][72];
    int k0 = blockIdx.y << 6, n0 = blockIdx.x << 6;
    int tid = threadIdx.x;
    int r = tid >> 2, c = (tid & 3) << 4;
    const float* ip = in + (size_t)(k0 + r) * N + n0 + c;
#pragma unroll
    for (int q = 0; q < 4; ++q) {
        f32x4 v = *(const f32x4*)(ip + 4 * q);
#pragma unroll
        for (int e = 0; e < 4; ++e) tile[r][c + 4 * q + e] = f2bf(v[e]);
    }
    __syncthreads();
    u16x8 o0, o1;
#pragma unroll
    for (int e = 0; e < 8; ++e) { o0[e] = tile[c + e][r]; o1[e] = tile[c + 8 + e][r]; }
    u16* op = out + (size_t)(n0 + r) * K + k0 + c;
    *(u16x8*)op = o0;
    *(u16x8*)(op + 8) = o1;
}

// ------- transpose+cast, 2-batch: in [K][N] f32 -> out bf16 [N][K] -----------
__global__ __launch_bounds__(256) void transpose2_k(const float* pa, const float* pb,
                                                    u16* __restrict__ dst0, size_t dsz,
                                                    int K, int N) {
    int z = blockIdx.z;
    const float* in = z ? pb : pa;
    u16* out = dst0 + (size_t)z * dsz;
    __shared__ u16 tile[64][72];
    int k0 = blockIdx.y << 6, n0 = blockIdx.x << 6;
    int tid = threadIdx.x;
    int r = tid >> 2, c = (tid & 3) << 4;
    const float* ip = in + (size_t)(k0 + r) * N + n0 + c;
#pragma unroll
    for (int q = 0; q < 4; ++q) {
        f32x4 v = *(const f32x4*)(ip + 4 * q);
#pragma unroll
        for (int e = 0; e < 4; ++e) tile[r][c + 4 * q + e] = f2bf(v[e]);
    }
    __syncthreads();
    u16x8 o0, o1;
#pragma unroll
    for (int e = 0; e < 8; ++e) { o0[e] = tile[c + e][r]; o1[e] = tile[c + 8 + e][r]; }
    u16* op = out + (size_t)(n0 + r) * K + k0 + c;
    *(u16x8*)op = o0;
    *(u16x8*)(op + 8) = o1;
}

// ------- V row-major [B,H,S,64] -> VT [B,H,64,S]; grid (16 st, 48 bh, 2 z) ---
__global__ __launch_bounds__(256) void vtrans_k(const u16* __restrict__ Vrow,
                                                u16* __restrict__ VT0) {
    int st = blockIdx.x, bh = blockIdx.y, z = blockIdx.z;
    const u16* src = Vrow + (size_t)z * EL + ((size_t)bh << 16) + (size_t)st * 64 * 64;
    u16* dst = VT0 + (size_t)z * 3 * EL + ((size_t)bh << 16) + st * 64;
    __shared__ u16 tile[64][72];
    int tid = threadIdx.x;
    int r = tid >> 2, c = (tid & 3) << 4;
    const u16* ip = src + (size_t)r * 64 + c;
    u16x8 a = *(const u16x8*)ip;
    u16x8 b = *(const u16x8*)(ip + 8);
#pragma unroll
    for (int e = 0; e < 8; ++e) { tile[r][c + e] = a[e]; tile[r][c + 8 + e] = b[e]; }
    __syncthreads();
    u16x8 o0, o1;
#pragma unroll
    for (int e = 0; e < 8; ++e) { o0[e] = tile[c + e][r]; o1[e] = tile[c + 8 + e][r]; }
    u16* op = dst + (size_t)r * 1024 + c;
    *(u16x8*)op = o0;
    *(u16x8*)(op + 8) = o1;
}

// ------- LayerNorm D=768, f32 in, bf16 out; 2-batch via blockIdx.y ----------
__global__ __launch_bounds__(256) void ln_k(const float* __restrict__ inX,
                                            const float* __restrict__ inY,
                                            const float* gX, const float* bX,
                                            const float* gY, const float* bY,
                                            u16* __restrict__ out0) {
    int z = blockIdx.y;
    const float* in = z ? inY : inX;
    const float* g = z ? gY : gX;
    const float* be = z ? bY : bX;
    u16* out = out0 + (size_t)z * EL;
    int row = blockIdx.x, tid = threadIdx.x;
    const float* p = in + (size_t)row * 768;
    float v0 = p[tid], v1 = p[tid + 256], v2 = p[tid + 512];
    float s = v0 + v1 + v2;
    float q = v0 * v0 + v1 * v1 + v2 * v2;
#pragma unroll
    for (int m = 1; m < 64; m <<= 1) { s += __shfl_xor(s, m); q += __shfl_xor(q, m); }
    __shared__ float red[8];
    int w = tid >> 6, lane = tid & 63;
    if (lane == 0) { red[w] = s; red[4 + w] = q; }
    __syncthreads();
    s = red[0] + red[1] + red[2] + red[3];
    q = red[4] + red[5] + red[6] + red[7];
    float mean = s * (1.0f / 768.0f);
    float var = q * (1.0f / 768.0f) - mean * mean;
    float rstd = rsqrtf(var + 1e-6f);
    u16* o = out + (size_t)row * 768;
    o[tid]       = f2bf((v0 - mean) * rstd * g[tid]       + be[tid]);
    o[tid + 256] = f2bf((v1 - mean) * rstd * g[tid + 256] + be[tid + 256]);
    o[tid + 512] = f2bf((v2 - mean) * rstd * g[tid + 512] + be[tid + 512]);
}

// ------- LayerNorm D=768, bf16 in, bf16 out (LN2 on x1/y1) ------------------
__global__ __launch_bounds__(256) void lnb_k(const u16* __restrict__ inX,
                                             const u16* __restrict__ inY,
                                             const float* gX, const float* bX,
                                             const float* gY, const float* bY,
                                             u16* __restrict__ out0) {
    int z = blockIdx.y;
    const u16* in = z ? inY : inX;
    const float* g = z ? gY : gX;
    const float* be = z ? bY : bX;
    u16* out = out0 + (size_t)z * EL;
    int row = blockIdx.x, tid = threadIdx.x;
    const u16* p = in + (size_t)row * 768;
    float v0 = b2f(p[tid]), v1 = b2f(p[tid + 256]), v2 = b2f(p[tid + 512]);
    float s = v0 + v1 + v2;
    float q = v0 * v0 + v1 * v1 + v2 * v2;
#pragma unroll
    for (int m = 1; m < 64; m <<= 1) { s += __shfl_xor(s, m); q += __shfl_xor(q, m); }
    __shared__ float red[8];
    int w = tid >> 6, lane = tid & 63;
    if (lane == 0) { red[w] = s; red[4 + w] = q; }
    __syncthreads();
    s = red[0] + red[1] + red[2] + red[3];
    q = red[4] + red[5] + red[6] + red[7];
    float mean = s * (1.0f / 768.0f);
    float var = q * (1.0f / 768.0f) - mean * mean;
    float rstd = rsqrtf(var + 1e-6f);
    u16* o = out + (size_t)row * 768;
    o[tid]       = f2bf((v0 - mean) * rstd * g[tid]       + be[tid]);
    o[tid + 256] = f2bf((v1 - mean) * rstd * g[tid + 256] + be[tid + 256]);
    o[tid + 512] = f2bf((v2 - mean) * rstd * g[tid + 512] + be[tid + 512]);
}

// ------- blend, 2-batch: a[z] = w1[z]*a[z] + w2[z]*b[z] ----------------------
__global__ __launch_bounds__(256) void blend_k(u16* __restrict__ a0,
                                               const u16* __restrict__ b0,
                                               const float* w11, const float* w12,
                                               const float* w21, const float* w22,
                                               int n8) {
    int z = blockIdx.z;
    u16* a = a0 + (size_t)z * EL;
    const u16* b = b0 + (size_t)z * EL;
    float wa = z ? *w21 : *w11, wb = z ? *w22 : *w12;
    for (int i = blockIdx.x * blockDim.x + threadIdx.x; i < n8;
         i += gridDim.x * blockDim.x) {
        u16x8 va = ((const u16x8*)a)[i];
        u16x8 vb = ((const u16x8*)b)[i];
        u16x8 r;
#pragma unroll
        for (int e = 0; e < 8; ++e) r[e] = f2bf(wa * b2f(va[e]) + wb * b2f(vb[e]));
        ((u16x8*)a)[i] = r;
    }
}

// ------- split-K combine: out = sum(parts) + b2[n] + x1(bf16) ----------------
__global__ __launch_bounds__(256) void combine_k(const float* __restrict__ parts,
                                                 int KS,
                                                 const u16* __restrict__ x1b,
                                                 const float* __restrict__ b2X,
                                                 const float* __restrict__ b2Y,
                                                 float* __restrict__ out, int n4tot) {
    int i = blockIdx.x * 256 + threadIdx.x;
    if (i >= n4tot) return;
    size_t e = (size_t)i * 4;
    f32x4 s = ((const f32x4*)parts)[i];
    for (int k = 1; k < KS; ++k)
        s += ((const f32x4*)(parts + (size_t)k * 2 * EL))[i];
    const float* bb = (e < EL) ? b2X : b2Y;
    int n = (int)(e % 768);
    ushort4 xv = ((const ushort4*)x1b)[i];
    f32x4 r;
    r[0] = s[0] + bb[n]     + b2f(xv.x);
    r[1] = s[1] + bb[n + 1] + b2f(xv.y);
    r[2] = s[2] + bb[n + 2] + b2f(xv.z);
    r[3] = s[3] + bb[n + 3] + b2f(xv.w);
    ((f32x4*)out)[i] = r;
}

#define EPI_GELU 3
#define EPI_WO 4     // resid f32 (X/Y), bias*(wa+wb), out bf16 (x1/y1)
#define EPI_MLP2 5   // resid bf16 (x1/y1), +bias, out f32 (d_out)
#define EPI_PART 6   // split-K partial: plain f32 store to parts[ks][z]

// ------- GEMM BM=128 BN=128 BK=32, 1D grid + xcd_map, optional split-K -------
template <int EPI>
__global__ __launch_bounds__(256) void gemm_k(
    const u16* __restrict__ A0, size_t Asz,
    const u16* __restrict__ B0, size_t Bsz,
    const float* __restrict__ bias0, const float* __restrict__ bias1,
    const void* __restrict__ r0, const void* __restrict__ r1,
    const float* s1a, const float* s1b, const float* s2a, const float* s2b,
    void* __restrict__ C0, size_t Csz,
    int M, int N, int K, int NN, int KS) {
    int m_, n_, z, ks;
    xcd_map(NN, m_, n_, z, ks);
    const int Kloc = K / KS;
    const u16* A = A0 + z * Asz;
    const u16* BT = B0 + z * Bsz;
    const float* bias = z ? bias1 : bias0;
    const float* residf = (const float*)(z ? r1 : r0);
    const u16* residb = (const u16*)(z ? r1 : r0);
    u16* Cb = (u16*)C0 + z * Csz;
    float* Cf = (float*)C0 + ((size_t)ks * 2 + z) * Csz;
    __shared__ u16 lA[2][4096];
    __shared__ u16 lB[2][4096];
    int tid = threadIdx.x;
    int bm0 = m_ << 7, bn0 = n_ << 7;
    int lane = tid & 63, wid = tid >> 6;
    int fr = lane & 15, g = lane >> 4;
    int wm = wid >> 1, wn = wid & 1;
    const u16* srcA0 = A + (size_t)(bm0 + (tid & 127)) * K + ks * Kloc + ((tid >> 7) << 3);
    const u16* srcA1 = srcA0 + 16;
    const u16* srcB0 = BT + (size_t)(bn0 + (tid & 127)) * K + ks * Kloc + ((tid >> 7) << 3);
    const u16* srcB1 = srcB0 + 16;
    auto STAGE = [&](int buf, int k0) {
        gld16(srcA0 + k0, &lA[buf][0] + tid * 8);
        gld16(srcA1 + k0, &lA[buf][0] + 2048 + tid * 8);
        gld16(srcB0 + k0, &lB[buf][0] + tid * 8);
        gld16(srcB1 + k0, &lB[buf][0] + 2048 + tid * 8);
    };
    f32x4 acc[4][4] = {};
    STAGE(0, 0);
    __syncthreads();
    int cur = 0;
    for (int k0 = 0; k0 < Kloc; k0 += 32) {
        if (k0 + 32 < Kloc) STAGE(cur ^ 1, k0 + 32);
        s16x8 af[4], bf[4];
#pragma unroll
        for (int i = 0; i < 4; ++i)
            af[i] = *(const s16x8*)&lA[cur][(g * 128 + wm * 64 + i * 16 + fr) * 8];
#pragma unroll
        for (int j = 0; j < 4; ++j)
            bf[j] = *(const s16x8*)&lB[cur][(g * 128 + wn * 64 + j * 16 + fr) * 8];
#pragma unroll
        for (int i = 0; i < 4; ++i)
#pragma unroll
            for (int j = 0; j < 4; ++j)
                acc[i][j] = mfma16(af[i], bf[j], acc[i][j]);
        __syncthreads();
        cur ^= 1;
    }
    float bscale = 1.0f;
    if (EPI == EPI_WO) bscale = z ? (s2a[0] + s2b[0]) : (s1a[0] + s1b[0]);
#pragma unroll
    for (int j = 0; j < 4; ++j) {
        int n = bn0 + wn * 64 + j * 16 + fr;
        float bv = 0.0f;
        if (EPI != EPI_PART) bv = bias[n] * bscale;
#pragma unroll
        for (int i = 0; i < 4; ++i) {
#pragma unroll
            for (int r = 0; r < 4; ++r) {
                int m = bm0 + wm * 64 + i * 16 + (g << 2) + r;
                size_t idx = (size_t)m * N + n;
                float v = acc[i][j][r] + bv;
                if (EPI == EPI_GELU) {
                    Cb[idx] = f2bf(gelu_f(v));
                } else if (EPI == EPI_WO) {
                    Cb[idx] = f2bf(v + residf[idx]);
                } else if (EPI == EPI_MLP2) {
                    Cf[idx] = v + b2f(residb[idx]);
                } else {
                    Cf[idx] = v;   // EPI_PART: partial, combined later
                }
            }
        }
    }
}

// ------- fused QKV GEMM. Q pre-scaled by 0.125*log2(e). ----------------------
// ALL segments store row-major head-split [B,H,S,64]; V transposed afterwards.
__global__ __launch_bounds__(256) void gemm_qkv_k(const u16* __restrict__ A0,
                                                  const u16* __restrict__ B0,
                                                  const float* bq, const float* bk,
                                                  const float* bv, const float* bqd,
                                                  const float* bkd, const float* bvd,
                                                  u16* __restrict__ Qd,
                                                  u16* __restrict__ Kd,
                                                  u16* __restrict__ Vd) {
    const int K = 768;
    int m_, n_, z, ks_;
    xcd_map(18, m_, n_, z, ks_);
    const u16* A = A0 + z * EL;
    const u16* BT = B0 + z * 3 * DDE;
    __shared__ u16 lA[2][4096];
    __shared__ u16 lB[2][4096];
    int tid = threadIdx.x;
    int bm0 = m_ << 7, bn0 = n_ << 7;
    int lane = tid & 63, wid = tid >> 6, wm = wid >> 1, wn = wid & 1;
    int fr = lane & 15, g = lane >> 4;
    const u16* srcA0 = A + (size_t)(bm0 + (tid & 127)) * K + ((tid >> 7) << 3);
    const u16* srcA1 = srcA0 + 16;
    const u16* srcB0 = BT + (size_t)(bn0 + (tid & 127)) * K + ((tid >> 7) << 3);
    const u16* srcB1 = srcB0 + 16;
    auto STAGE = [&](int buf, int k0) {
        gld16(srcA0 + k0, &lA[buf][0] + tid * 8);
        gld16(srcA1 + k0, &lA[buf][0] + 2048 + tid * 8);
        gld16(srcB0 + k0, &lB[buf][0] + tid * 8);
        gld16(srcB1 + k0, &lB[buf][0] + 2048 + tid * 8);
    };
    f32x4 acc[4][4] = {};
    STAGE(0, 0);
    __syncthreads();
    int cur = 0;
    for (int k0 = 0; k0 < K; k0 += 32) {
        if (k0 + 32 < K) STAGE(cur ^ 1, k0 + 32);
        s16x8 af[4], bf[4];
#pragma unroll
        for (int i = 0; i < 4; ++i)
            af[i] = *(const s16x8*)&lA[cur][(g * 128 + wm * 64 + i * 16 + fr) * 8];
#pragma unroll
        for (int j = 0; j < 4; ++j)
            bf[j] = *(const s16x8*)&lB[cur][(g * 128 + wn * 64 + j * 16 + fr) * 8];
#pragma unroll
        for (int i = 0; i < 4; ++i)
#pragma unroll
            for (int j = 0; j < 4; ++j)
                acc[i][j] = mfma16(af[i], bf[j], acc[i][j]);
        __syncthreads();
        cur ^= 1;
    }
    int seg = bn0 / 768;
    const float* bp = seg == 0 ? (z ? bqd : bq) : seg == 1 ? (z ? bkd : bk) : (z ? bvd : bv);
    u16* out;
    size_t zoff;
    if (seg == 0)      { out = Qd; zoff = (size_t)z * 3 * EL; }
    else if (seg == 1) { out = Kd; zoff = (size_t)z * 3 * EL; }
    else               { out = Vd; zoff = (size_t)z * EL; }
    int nbase = bn0 - seg * 768;
    const float qs = (seg == 0) ? 0.180336880f : 1.0f;  // 0.125 * log2(e)
#pragma unroll
    for (int j = 0; j < 4; ++j) {
        int nn = nbase + wn * 64 + j * 16 + fr;
        float bvl = bp[nn];
        int hh = nn >> 6, hd = nn & 63;
#pragma unroll
        for (int i = 0; i < 4; ++i) {
#pragma unroll
            for (int r = 0; r < 4; ++r) {
                int m = bm0 + wm * 64 + i * 16 + (g << 2) + r;
                int bb = m >> 10, ss = m & 1023;
                size_t o = zoff + (((size_t)(bb * 12 + hh)) << 16) + ((size_t)ss << 6) + hd;
                out[o] = f2bf((acc[i][j][r] + bvl) * qs);
            }
        }
    }
}

// ------- fused attention v9: v8 + double-buffered K/V with prefetch ----------
// STAGE(t+1) issues right after the barrier, BEFORE computing tile t, so the
// global->LDS loads fly during the 32 MFMAs + softmax (the gemm_k pattern;
// v8 drained vmcnt to 0 before every compute phase). One barrier per tile.
// K chunk swizzle c^=(row&7); V chunk swizzle c^=((row>>1)&3) (both verified).
__global__ __launch_bounds__(256) void attn_k(const u16* __restrict__ Qx,
                                              const u16* __restrict__ Kx,
                                              const u16* __restrict__ VTx,
                                              const u16* __restrict__ Qy,
                                              const u16* __restrict__ Ky,
                                              const u16* __restrict__ VTy,
                                              u16* __restrict__ csx,
                                              u16* __restrict__ ccx,
                                              u16* __restrict__ csy,
                                              u16* __restrict__ ccy) {
    int p = blockIdx.x;
    int lg = (p & 7) * 192 + (p >> 3);       // contiguous logical ids per XCD
    int sg = lg >> 4, wi = lg & 15;          // supergroup = K/V-sharing pair
    int qt = wi & 7, sub = wi >> 3;
    int pairi = sg / 48, bh = sg % 48;
    int cfg = pairi == 0 ? (sub ? 3 : 0) : (sub ? 2 : 1);
    const u16 *Qp, *Kp, *Vp;
    u16* Op;
    if (cfg == 0)      { Qp = Qx; Kp = Kx; Vp = VTx; Op = csx; }
    else if (cfg == 1) { Qp = Qy; Kp = Ky; Vp = VTy; Op = csy; }
    else if (cfg == 2) { Qp = Qx; Kp = Ky; Vp = VTy; Op = ccx; }
    else               { Qp = Qy; Kp = Kx; Vp = VTx; Op = ccy; }
    const u16* Qh = Qp + ((size_t)bh << 16);
    const u16* Kh = Kp + ((size_t)bh << 16);
    const u16* Vh = Vp + ((size_t)bh << 16);
    int b = bh / 12, h = bh % 12;
    int tid = threadIdx.x, lane = tid & 63, w = tid >> 6;
    int q0 = qt * 128 + w * 32;
    int fr = lane & 15, ko = (lane >> 4) << 3, g = lane >> 4;
    bool glo = lane < 32;
    int srcA = fr + ((lane & 16) << 1);
    int srcB = srcA + 16;

    __shared__ u16 kls[8192];   // 2 buf x 2 x (32 keys x 64 d), chunk-swizzled
    __shared__ u16 vls[8192];   // 2 buf x 2 x (64 d x 32 keys), chunk-swizzled

    s16x8 qf[2][2];
#pragma unroll
    for (int s = 0; s < 2; ++s) {
        const u16* qp = Qh + (size_t)(q0 + s * 16 + fr) * 64 + ko;
        qf[s][0] = *(const s16x8*)qp;
        qf[s][1] = *(const s16x8*)(qp + 32);
    }

    f32x4 acc[2][4] = {};
    float lsum[2] = {0.f, 0.f};
    f32x4 zz = {0.f, 0.f, 0.f, 0.f};

    int krow = tid >> 3, kpc = tid & 7;
    int kgc = kpc ^ (krow & 7);              // K source-chunk swizzle
    int vdr = tid >> 2, vpv = tid & 3;
    int vgc = vpv ^ ((vdr >> 1) & 3);        // V source-chunk swizzle
    int cK0 = ((fr << 3) + (g ^ (fr & 7))) << 3;
    int cK1 = ((fr << 3) + ((g + 4) ^ (fr & 7))) << 3;
    int cK2 = (((fr + 16) << 3) + (g ^ (fr & 7))) << 3;
    int cK3 = (((fr + 16) << 3) + ((g + 4) ^ (fr & 7))) << 3;
    int cVg = (g ^ ((fr >> 1) & 3)) << 3;    // V read-chunk

    auto STAGE = [&](int buf, int kb) {
        int lb = buf * 4096 + tid * 8;
        gld16(Kh + (size_t)(kb + krow) * 64 + kgc * 8, &kls[lb]);
        gld16(Kh + (size_t)(kb + 32 + krow) * 64 + kgc * 8, &kls[lb + 2048]);
        gld16(Vh + (size_t)vdr * 1024 + kb + vgc * 8, &vls[lb]);
        gld16(Vh + (size_t)vdr * 1024 + kb + 32 + vgc * 8, &vls[lb + 2048]);
    };

    auto HALF = [&](int base) {
        s16x8 Kf0 = *(const s16x8*)&kls[base + cK0];
        s16x8 Kf1 = *(const s16x8*)&kls[base + cK1];
        s16x8 Kf2 = *(const s16x8*)&kls[base + cK2];
        s16x8 Kf3 = *(const s16x8*)&kls[base + cK3];
        s16x8 Vf[4];
#pragma unroll
        for (int t4 = 0; t4 < 4; ++t4)
            Vf[t4] = *(const s16x8*)&vls[base + ((t4 * 16 + fr) << 5) + cVg];
        s16x8 pa[2];
#pragma unroll
        for (int s = 0; s < 2; ++s) {
            __builtin_amdgcn_s_setprio(1);
            f32x4 t0 = mfma16(Kf0, qf[s][0], zz);
            t0 = mfma16(Kf1, qf[s][1], t0);
            f32x4 t1 = mfma16(Kf2, qf[s][0], zz);
            t1 = mfma16(Kf3, qf[s][1], t1);
            __builtin_amdgcn_s_setprio(0);
            float p00 = EXP2(t0[0]), p01 = EXP2(t0[1]);
            float p02 = EXP2(t0[2]), p03 = EXP2(t0[3]);
            float p10 = EXP2(t1[0]), p11 = EXP2(t1[1]);
            float p12 = EXP2(t1[2]), p13 = EXP2(t1[3]);
            lsum[s] += (p00 + p01 + p02 + p03) + (p10 + p11 + p12 + p13);
            unsigned w0, w1, w2, w3;
            asm("v_cvt_pk_bf16_f32 %0, %1, %2" : "=v"(w0) : "v"(p00), "v"(p01));
            asm("v_cvt_pk_bf16_f32 %0, %1, %2" : "=v"(w1) : "v"(p02), "v"(p03));
            asm("v_cvt_pk_bf16_f32 %0, %1, %2" : "=v"(w2) : "v"(p10), "v"(p11));
            asm("v_cvt_pk_bf16_f32 %0, %1, %2" : "=v"(w3) : "v"(p12), "v"(p13));
            int e0 = __shfl((int)w0, srcA), e1 = __shfl((int)w1, srcA);
            int e2 = __shfl((int)w0, srcB), e3 = __shfl((int)w1, srcB);
            int f0 = __shfl((int)w2, srcA), f1 = __shfl((int)w3, srcA);
            int f2 = __shfl((int)w2, srcB), f3 = __shfl((int)w3, srcB);
            int4 wd;
            wd.x = glo ? e0 : f0;
            wd.y = glo ? e1 : f1;
            wd.z = glo ? e2 : f2;
            wd.w = glo ? e3 : f3;
            pa[s] = __builtin_bit_cast(s16x8, wd);
        }
        __builtin_amdgcn_s_setprio(1);
#pragma unroll
        for (int t4 = 0; t4 < 4; ++t4) {
            acc[0][t4] = mfma16(pa[0], Vf[t4], acc[0][t4]);
            acc[1][t4] = mfma16(pa[1], Vf[t4], acc[1][t4]);
        }
        __builtin_amdgcn_s_setprio(0);
    };

    STAGE(0, 0);
    int cur = 0;
    for (int kb = 0; kb < 1024; kb += 64) {
        __syncthreads();   // buffer `cur` staged; all reads of cur^1 finished
        if (kb + 64 < 1024) STAGE(cur ^ 1, kb + 64);  // fly during compute
        HALF(cur * 4096);
        HALF(cur * 4096 + 2048);
        cur ^= 1;
    }

    float invv[2][4];
#pragma unroll
    for (int s = 0; s < 2; ++s) {
        float l = lsum[s];
        l += __shfl_xor(l, 16);
        l += __shfl_xor(l, 32);
        float inv = 1.0f / l;
#pragma unroll
        for (int r = 0; r < 4; ++r)
            invv[s][r] = __shfl(inv, ((lane >> 4) << 2) + r);
    }
#pragma unroll
    for (int s = 0; s < 2; ++s) {
        u16* ob = Op + (size_t)(b * 1024 + q0 + s * 16 + ((lane >> 4) << 2)) * 768 + h * 64 + fr;
#pragma unroll
        for (int t4 = 0; t4 < 4; ++t4)
#pragma unroll
            for (int r = 0; r < 4; ++r)
                ob[(size_t)r * 768 + t4 * 16] = f2bf(acc[s][t4][r] * invv[s][r]);
    }
}

// -----------------------------------------------------------------------------
extern "C" void kernel_launch(void* const* d_in, const int* in_sizes, int n_in,
                              void* d_out, int out_size, void* d_ws, size_t ws_size,
                              hipStream_t stream) {
    (void)in_sizes; (void)n_in; (void)out_size;
    const float* X    = (const float*)d_in[0];
    const float* Y    = (const float*)d_in[1];
    const float* l1xg = (const float*)d_in[2];
    const float* l1xb = (const float*)d_in[3];
    const float* l1yg = (const float*)d_in[4];
    const float* l1yb = (const float*)d_in[5];
    const float* Wq   = (const float*)d_in[6];
    const float* bq   = (const float*)d_in[7];
    const float* Wk   = (const float*)d_in[8];
    const float* bk   = (const float*)d_in[9];
    const float* Wv   = (const float*)d_in[10];
    const float* bv   = (const float*)d_in[11];
    const float* Wo   = (const float*)d_in[12];
    const float* bo   = (const float*)d_in[13];
    const float* Wqd  = (const float*)d_in[14];
    const float* bqd  = (const float*)d_in[15];
    const float* Wkd  = (const float*)d_in[16];
    const float* bkd  = (const float*)d_in[17];
    const float* Wvd  = (const float*)d_in[18];
    const float* bvd  = (const float*)d_in[19];
    const float* Wod  = (const float*)d_in[20];
    const float* bod  = (const float*)d_in[21];
    const float* w11  = (const float*)d_in[22];
    const float* w12  = (const float*)d_in[23];
    const float* w21  = (const float*)d_in[24];
    const float* w22  = (const float*)d_in[25];
    const float* l2xg = (const float*)d_in[26];
    const float* l2xb = (const float*)d_in[27];
    const float* l2yg = (const float*)d_in[28];
    const float* l2yb = (const float*)d_in[29];
    const float* W1   = (const float*)d_in[30];
    const float* b1   = (const float*)d_in[31];
    const float* W2   = (const float*)d_in[32];
    const float* b2   = (const float*)d_in[33];
    const float* W1d  = (const float*)d_in[34];
    const float* b1d  = (const float*)d_in[35];
    const float* W2d  = (const float*)d_in[36];
    const float* b2d  = (const float*)d_in[37];

    u16* ws = (u16*)d_ws;
    u16* qkvT = ws;
    u16* WoT  = qkvT + 6 * DDE;
    u16* W1T  = WoT + 2 * DDE;
    u16* W2T  = W1T + 2 * DFE;
    u16* xn   = W2T + 2 * DFE;   // 2E: xn,yn (also LN2 outs later)
    u16* Qx   = xn + 2 * EL;     // 6E: Qx,Kx,VTx,Qy,Ky,VTy ; h aliases (8E)
    u16* cs   = Qx + 6 * EL;     // 4E: csx,csy,ccx,ccy (also Vrow scratch)
    u16* x1   = cs + 4 * EL;     // 2E bf16: x1,y1
    u16* Kx = Qx + EL;
    u16* VTx = Qx + 2 * EL;
    u16* h = Qx;                 // MLP hidden: x at h, y at h+4E
    u16* y1 = x1 + EL;
    u16* wsEnd = x1 + 2 * EL;    // end of fixed layout
    u16* Vrow = cs;              // V row-major scratch (2E), dead before attn writes cs

    float* out_x = (float*)d_out;

    float* parts = (float*)wsEnd;
    size_t baseBytes = (size_t)(wsEnd - ws) * 2;
    size_t partBytes = 2 * EL * sizeof(float);
    int KS = 1;
    if (ws_size >= baseBytes + 4 * partBytes) KS = 4;
    else if (ws_size >= baseBytes + 2 * partBytes) KS = 2;

    dim3 tb(256);
    transpose8_k<<<dim3(12, 12, 8), tb, 0, stream>>>(Wq, Wk, Wv, Wqd, Wkd, Wvd, Wo, Wod, qkvT);
    transpose2_k<<<dim3(48, 12, 2), tb, 0, stream>>>(W1, W1d, W1T, DFE, 768, 3072);
    transpose2_k<<<dim3(12, 48, 2), tb, 0, stream>>>(W2, W2d, W2T, DFE, 3072, 768);
    ln_k<<<dim3(4096, 2), tb, 0, stream>>>(X, Y, l1xg, l1xb, l1yg, l1yb, xn);
    gemm_qkv_k<<<1152, tb, 0, stream>>>(xn, qkvT, bq, bk, bv, bqd, bkd, bvd,
                                        Qx, Kx, Vrow);
    vtrans_k<<<dim3(16, 48, 2), tb, 0, stream>>>(Vrow, VTx);
    attn_k<<<4 * 48 * 8, tb, 0, stream>>>(Qx, Kx, VTx, Qx + 3 * EL, Qx + 4 * EL, Qx + 5 * EL,
                                          cs, cs + 2 * EL, cs + EL, cs + 3 * EL);
    int n8 = (int)(EL / 8);
    blend_k<<<dim3(1536, 1, 2), tb, 0, stream>>>(cs, cs + 2 * EL, w11, w12, w21, w22, n8);
    gemm_k<EPI_WO><<<384, tb, 0, stream>>>(
        cs, EL, WoT, DDE, bo, bod, X, Y, w11, w12, w21, w22, x1, EL,
        4096, 768, 768, 6, 1);
    lnb_k<<<dim3(4096, 2), tb, 0, stream>>>(x1, y1, l2xg, l2xb, l2yg, l2yb, xn);
    gemm_k<EPI_GELU><<<1536, tb, 0, stream>>>(
        xn, EL, W1T, DFE, b1, b1d, nullptr, nullptr, nullptr, nullptr, nullptr, nullptr,
        h, 4 * EL, 4096, 3072, 768, 24, 1);
    if (KS > 1) {
        gemm_k<EPI_PART><<<384 * KS, tb, 0, stream>>>(
            h, 4 * EL, W2T, DFE, nullptr, nullptr, nullptr, nullptr,
            nullptr, nullptr, nullptr, nullptr,
            parts, EL, 4096, 768, 3072, 6, KS);
        int n4 = (int)(2 * EL / 4);
        combine_k<<<(n4 + 255) / 256, tb, 0, stream>>>(parts, KS, x1, b2, b2d,
                                                       out_x, n4);
    } else {
        gemm_k<EPI_MLP2><<<384, tb, 0, stream>>>(
            h, 4 * EL, W2T, DFE, b2, b2d, x1, y1,
            nullptr, nullptr, nullptr, nullptr,
            out_x, EL, 4096, 768, 3072, 6, 1);
    }
}

// Round 24
// 410.517 us; speedup vs baseline: 1.0653x; 1.0306x over previous
//
#include <hip/hip_runtime.h>

typedef unsigned short u16;
typedef unsigned short u16x8 __attribute__((ext_vector_type(8)));
typedef short s16x8 __attribute__((ext_vector_type(8)));
typedef float f32x4 __attribute__((ext_vector_type(4)));

#define EL ((size_t)3145728)       // 4096*768
#define DDE ((size_t)589824)       // 768*768
#define DFE ((size_t)2359296)      // 768*3072

#if __has_builtin(__builtin_amdgcn_exp2f)
#define EXP2(x) __builtin_amdgcn_exp2f(x)
#else
#define EXP2(x) __expf((x) * 0.6931471805599453f)
#endif

__device__ __forceinline__ float b2f(u16 u) {
    return __builtin_bit_cast(float, (unsigned)u << 16);
}
__device__ __forceinline__ u16 f2bf(float f) {
    unsigned x = __builtin_bit_cast(unsigned, f);
    return (u16)((x + 0x7fffu + ((x >> 16) & 1u)) >> 16);
}
__device__ __forceinline__ float gelu_f(float x) {
    float t = x + 0.044715f * x * x * x;
    return x * __builtin_amdgcn_rcpf(1.0f + EXP2(-2.302207417f * t));
}
__device__ __forceinline__ f32x4 mfma16(s16x8 a, s16x8 b, f32x4 c) {
    return __builtin_amdgcn_mfma_f32_16x16x32_bf16(a, b, c, 0, 0, 0);
}
__device__ __forceinline__ void gld16(const u16* g, u16* l) {
    __builtin_amdgcn_global_load_lds((const __attribute__((address_space(1))) void*)g,
                                     (__attribute__((address_space(3))) void*)l,
                                     16, 0, 0);
}
// XCD panel-ownership map: 1D grid T (T%8==0, (T/8)%NN==0).
__device__ __forceinline__ void xcd_map(int NN, int& m, int& n, int& z, int& ks) {
    int p = blockIdx.x, T = gridDim.x;
    int ppx = T >> 3;
    int xcd = p & 7, l = p >> 3;
    int panel = l / NN;
    n = l - panel * NN;
    int gp = xcd * (ppx / NN) + panel;
    m = gp & 31;
    z = (gp >> 5) & 1;
    ks = gp >> 6;
}

// ------- transpose+cast, 8-batch (768x768 each): z selects src; dst+z*DDE ----
__global__ __launch_bounds__(256) void transpose8_k(const float* p0, const float* p1,
                                                    const float* p2, const float* p3,
                                                    const float* p4, const float* p5,
                                                    const float* p6, const float* p7,
                                                    u16* __restrict__ dst0) {
    int z = blockIdx.z;
    const float* in = z == 0 ? p0 : z == 1 ? p1 : z == 2 ? p2 : z == 3 ? p3
                    : z == 4 ? p4 : z == 5 ? p5 : z == 6 ? p6 : p7;
    u16* out = dst0 + (size_t)z * DDE;
    const int K = 768, N = 768;
    __shared__ u16 tile[64][72];
    int k0 = blockIdx.y << 6, n0 = blockIdx.x << 6;
    int tid = threadIdx.x;
    int r = tid >> 2, c = (tid & 3) << 4;
    const float* ip = in + (size_t)(k0 + r) * N + n0 + c;
#pragma unroll
    for (int q = 0; q < 4; ++q) {
        f32x4 v = *(const f32x4*)(ip + 4 * q);
#pragma unroll
        for (int e = 0; e < 4; ++e) tile[r][c + 4 * q + e] = f2bf(v[e]);
    }
    __syncthreads();
    u16x8 o0, o1;
#pragma unroll
    for (int e = 0; e < 8; ++e) { o0[e] = tile[c + e][r]; o1[e] = tile[c + 8 + e][r]; }
    u16* op = out + (size_t)(n0 + r) * K + k0 + c;
    *(u16x8*)op = o0;
    *(u16x8*)(op + 8) = o1;
}

// ------- transpose+cast, 2-batch: in [K][N] f32 -> out bf16 [N][K] -----------
__global__ __launch_bounds__(256) void transpose2_k(const float* pa, const float* pb,
                                                    u16* __restrict__ dst0, size_t dsz,
                                                    int K, int N) {
    int z = blockIdx.z;
    const float* in = z ? pb : pa;
    u16* out = dst0 + (size_t)z * dsz;
    __shared__ u16 tile[64][72];
    int k0 = blockIdx.y << 6, n0 = blockIdx.x << 6;
    int tid = threadIdx.x;
    int r = tid >> 2, c = (tid & 3) << 4;
    const float* ip = in + (size_t)(k0 + r) * N + n0 + c;
#pragma unroll
    for (int q = 0; q < 4; ++q) {
        f32x4 v = *(const f32x4*)(ip + 4 * q);
#pragma unroll
        for (int e = 0; e < 4; ++e) tile[r][c + 4 * q + e] = f2bf(v[e]);
    }
    __syncthreads();
    u16x8 o0, o1;
#pragma unroll
    for (int e = 0; e < 8; ++e) { o0[e] = tile[c + e][r]; o1[e] = tile[c + 8 + e][r]; }
    u16* op = out + (size_t)(n0 + r) * K + k0 + c;
    *(u16x8*)op = o0;
    *(u16x8*)(op + 8) = o1;
}

// ------- V row-major [B,H,S,64] -> VT [B,H,64,S]; grid (16 st, 48 bh, 2 z) ---
__global__ __launch_bounds__(256) void vtrans_k(const u16* __restrict__ Vrow,
                                                u16* __restrict__ VT0) {
    int st = blockIdx.x, bh = blockIdx.y, z = blockIdx.z;
    const u16* src = Vrow + (size_t)z * EL + ((size_t)bh << 16) + (size_t)st * 64 * 64;
    u16* dst = VT0 + (size_t)z * 3 * EL + ((size_t)bh << 16) + st * 64;
    __shared__ u16 tile[64][72];
    int tid = threadIdx.x;
    int r = tid >> 2, c = (tid & 3) << 4;
    const u16* ip = src + (size_t)r * 64 + c;
    u16x8 a = *(const u16x8*)ip;
    u16x8 b = *(const u16x8*)(ip + 8);
#pragma unroll
    for (int e = 0; e < 8; ++e) { tile[r][c + e] = a[e]; tile[r][c + 8 + e] = b[e]; }
    __syncthreads();
    u16x8 o0, o1;
#pragma unroll
    for (int e = 0; e < 8; ++e) { o0[e] = tile[c + e][r]; o1[e] = tile[c + 8 + e][r]; }
    u16* op = dst + (size_t)r * 1024 + c;
    *(u16x8*)op = o0;
    *(u16x8*)(op + 8) = o1;
}

// ------- LayerNorm D=768, f32 in, bf16 out; 2-batch via blockIdx.y ----------
__global__ __launch_bounds__(256) void ln_k(const float* __restrict__ inX,
                                            const float* __restrict__ inY,
                                            const float* gX, const float* bX,
                                            const float* gY, const float* bY,
                                            u16* __restrict__ out0) {
    int z = blockIdx.y;
    const float* in = z ? inY : inX;
    const float* g = z ? gY : gX;
    const float* be = z ? bY : bX;
    u16* out = out0 + (size_t)z * EL;
    int row = blockIdx.x, tid = threadIdx.x;
    const float* p = in + (size_t)row * 768;
    float v0 = p[tid], v1 = p[tid + 256], v2 = p[tid + 512];
    float s = v0 + v1 + v2;
    float q = v0 * v0 + v1 * v1 + v2 * v2;
#pragma unroll
    for (int m = 1; m < 64; m <<= 1) { s += __shfl_xor(s, m); q += __shfl_xor(q, m); }
    __shared__ float red[8];
    int w = tid >> 6, lane = tid & 63;
    if (lane == 0) { red[w] = s; red[4 + w] = q; }
    __syncthreads();
    s = red[0] + red[1] + red[2] + red[3];
    q = red[4] + red[5] + red[6] + red[7];
    float mean = s * (1.0f / 768.0f);
    float var = q * (1.0f / 768.0f) - mean * mean;
    float rstd = rsqrtf(var + 1e-6f);
    u16* o = out + (size_t)row * 768;
    o[tid]       = f2bf((v0 - mean) * rstd * g[tid]       + be[tid]);
    o[tid + 256] = f2bf((v1 - mean) * rstd * g[tid + 256] + be[tid + 256]);
    o[tid + 512] = f2bf((v2 - mean) * rstd * g[tid + 512] + be[tid + 512]);
}

// ------- LayerNorm D=768, bf16 in, bf16 out (LN2 on x1/y1) ------------------
__global__ __launch_bounds__(256) void lnb_k(const u16* __restrict__ inX,
                                             const u16* __restrict__ inY,
                                             const float* gX, const float* bX,
                                             const float* gY, const float* bY,
                                             u16* __restrict__ out0) {
    int z = blockIdx.y;
    const u16* in = z ? inY : inX;
    const float* g = z ? gY : gX;
    const float* be = z ? bY : bX;
    u16* out = out0 + (size_t)z * EL;
    int row = blockIdx.x, tid = threadIdx.x;
    const u16* p = in + (size_t)row * 768;
    float v0 = b2f(p[tid]), v1 = b2f(p[tid + 256]), v2 = b2f(p[tid + 512]);
    float s = v0 + v1 + v2;
    float q = v0 * v0 + v1 * v1 + v2 * v2;
#pragma unroll
    for (int m = 1; m < 64; m <<= 1) { s += __shfl_xor(s, m); q += __shfl_xor(q, m); }
    __shared__ float red[8];
    int w = tid >> 6, lane = tid & 63;
    if (lane == 0) { red[w] = s; red[4 + w] = q; }
    __syncthreads();
    s = red[0] + red[1] + red[2] + red[3];
    q = red[4] + red[5] + red[6] + red[7];
    float mean = s * (1.0f / 768.0f);
    float var = q * (1.0f / 768.0f) - mean * mean;
    float rstd = rsqrtf(var + 1e-6f);
    u16* o = out + (size_t)row * 768;
    o[tid]       = f2bf((v0 - mean) * rstd * g[tid]       + be[tid]);
    o[tid + 256] = f2bf((v1 - mean) * rstd * g[tid + 256] + be[tid + 256]);
    o[tid + 512] = f2bf((v2 - mean) * rstd * g[tid + 512] + be[tid + 512]);
}

// ------- blend, 2-batch: a[z] = w1[z]*a[z] + w2[z]*b[z] ----------------------
__global__ __launch_bounds__(256) void blend_k(u16* __restrict__ a0,
                                               const u16* __restrict__ b0,
                                               const float* w11, const float* w12,
                                               const float* w21, const float* w22,
                                               int n8) {
    int z = blockIdx.z;
    u16* a = a0 + (size_t)z * EL;
    const u16* b = b0 + (size_t)z * EL;
    float wa = z ? *w21 : *w11, wb = z ? *w22 : *w12;
    for (int i = blockIdx.x * blockDim.x + threadIdx.x; i < n8;
         i += gridDim.x * blockDim.x) {
        u16x8 va = ((const u16x8*)a)[i];
        u16x8 vb = ((const u16x8*)b)[i];
        u16x8 r;
#pragma unroll
        for (int e = 0; e < 8; ++e) r[e] = f2bf(wa * b2f(va[e]) + wb * b2f(vb[e]));
        ((u16x8*)a)[i] = r;
    }
}

// ------- split-K combine: out = sum(parts) + b2[n] + x1(bf16) ----------------
__global__ __launch_bounds__(256) void combine_k(const float* __restrict__ parts,
                                                 int KS,
                                                 const u16* __restrict__ x1b,
                                                 const float* __restrict__ b2X,
                                                 const float* __restrict__ b2Y,
                                                 float* __restrict__ out, int n4tot) {
    int i = blockIdx.x * 256 + threadIdx.x;
    if (i >= n4tot) return;
    size_t e = (size_t)i * 4;
    f32x4 s = ((const f32x4*)parts)[i];
    for (int k = 1; k < KS; ++k)
        s += ((const f32x4*)(parts + (size_t)k * 2 * EL))[i];
    const float* bb = (e < EL) ? b2X : b2Y;
    int n = (int)(e % 768);
    ushort4 xv = ((const ushort4*)x1b)[i];
    f32x4 r;
    r[0] = s[0] + bb[n]     + b2f(xv.x);
    r[1] = s[1] + bb[n + 1] + b2f(xv.y);
    r[2] = s[2] + bb[n + 2] + b2f(xv.z);
    r[3] = s[3] + bb[n + 3] + b2f(xv.w);
    ((f32x4*)out)[i] = r;
}

#define EPI_GELU 3
#define EPI_WO 4     // resid f32 (X/Y), bias*(wa+wb), out bf16 (x1/y1)
#define EPI_MLP2 5   // resid bf16 (x1/y1), +bias, out f32 (d_out)
#define EPI_PART 6   // split-K partial: plain f32 store to parts[ks][z]

// ------- GEMM BM=128 BN=128 BK=32, 1D grid + xcd_map, optional split-K -------
template <int EPI>
__global__ __launch_bounds__(256) void gemm_k(
    const u16* __restrict__ A0, size_t Asz,
    const u16* __restrict__ B0, size_t Bsz,
    const float* __restrict__ bias0, const float* __restrict__ bias1,
    const void* __restrict__ r0, const void* __restrict__ r1,
    const float* s1a, const float* s1b, const float* s2a, const float* s2b,
    void* __restrict__ C0, size_t Csz,
    int M, int N, int K, int NN, int KS) {
    int m_, n_, z, ks;
    xcd_map(NN, m_, n_, z, ks);
    const int Kloc = K / KS;
    const u16* A = A0 + z * Asz;
    const u16* BT = B0 + z * Bsz;
    const float* bias = z ? bias1 : bias0;
    const float* residf = (const float*)(z ? r1 : r0);
    const u16* residb = (const u16*)(z ? r1 : r0);
    u16* Cb = (u16*)C0 + z * Csz;
    float* Cf = (float*)C0 + ((size_t)ks * 2 + z) * Csz;
    __shared__ u16 lA[2][4096];
    __shared__ u16 lB[2][4096];
    int tid = threadIdx.x;
    int bm0 = m_ << 7, bn0 = n_ << 7;
    int lane = tid & 63, wid = tid >> 6;
    int fr = lane & 15, g = lane >> 4;
    int wm = wid >> 1, wn = wid & 1;
    const u16* srcA0 = A + (size_t)(bm0 + (tid & 127)) * K + ks * Kloc + ((tid >> 7) << 3);
    const u16* srcA1 = srcA0 + 16;
    const u16* srcB0 = BT + (size_t)(bn0 + (tid & 127)) * K + ks * Kloc + ((tid >> 7) << 3);
    const u16* srcB1 = srcB0 + 16;
    auto STAGE = [&](int buf, int k0) {
        gld16(srcA0 + k0, &lA[buf][0] + tid * 8);
        gld16(srcA1 + k0, &lA[buf][0] + 2048 + tid * 8);
        gld16(srcB0 + k0, &lB[buf][0] + tid * 8);
        gld16(srcB1 + k0, &lB[buf][0] + 2048 + tid * 8);
    };
    f32x4 acc[4][4] = {};
    STAGE(0, 0);
    __syncthreads();
    int cur = 0;
    for (int k0 = 0; k0 < Kloc; k0 += 32) {
        if (k0 + 32 < Kloc) STAGE(cur ^ 1, k0 + 32);
        s16x8 af[4], bf[4];
#pragma unroll
        for (int i = 0; i < 4; ++i)
            af[i] = *(const s16x8*)&lA[cur][(g * 128 + wm * 64 + i * 16 + fr) * 8];
#pragma unroll
        for (int j = 0; j < 4; ++j)
            bf[j] = *(const s16x8*)&lB[cur][(g * 128 + wn * 64 + j * 16 + fr) * 8];
#pragma unroll
        for (int i = 0; i < 4; ++i)
#pragma unroll
            for (int j = 0; j < 4; ++j)
                acc[i][j] = mfma16(af[i], bf[j], acc[i][j]);
        __syncthreads();
        cur ^= 1;
    }
    float bscale = 1.0f;
    if (EPI == EPI_WO) bscale = z ? (s2a[0] + s2b[0]) : (s1a[0] + s1b[0]);
#pragma unroll
    for (int j = 0; j < 4; ++j) {
        int n = bn0 + wn * 64 + j * 16 + fr;
        float bv = 0.0f;
        if (EPI != EPI_PART) bv = bias[n] * bscale;
#pragma unroll
        for (int i = 0; i < 4; ++i) {
#pragma unroll
            for (int r = 0; r < 4; ++r) {
                int m = bm0 + wm * 64 + i * 16 + (g << 2) + r;
                size_t idx = (size_t)m * N + n;
                float v = acc[i][j][r] + bv;
                if (EPI == EPI_GELU) {
                    Cb[idx] = f2bf(gelu_f(v));
                } else if (EPI == EPI_WO) {
                    Cb[idx] = f2bf(v + residf[idx]);
                } else if (EPI == EPI_MLP2) {
                    Cf[idx] = v + b2f(residb[idx]);
                } else {
                    Cf[idx] = v;   // EPI_PART: partial, combined later
                }
            }
        }
    }
}

// ------- fused QKV GEMM. Q pre-scaled by 0.125*log2(e). ----------------------
// ALL segments store row-major head-split [B,H,S,64]; V transposed afterwards.
__global__ __launch_bounds__(256) void gemm_qkv_k(const u16* __restrict__ A0,
                                                  const u16* __restrict__ B0,
                                                  const float* bq, const float* bk,
                                                  const float* bv, const float* bqd,
                                                  const float* bkd, const float* bvd,
                                                  u16* __restrict__ Qd,
                                                  u16* __restrict__ Kd,
                                                  u16* __restrict__ Vd) {
    const int K = 768;
    int m_, n_, z, ks_;
    xcd_map(18, m_, n_, z, ks_);
    const u16* A = A0 + z * EL;
    const u16* BT = B0 + z * 3 * DDE;
    __shared__ u16 lA[2][4096];
    __shared__ u16 lB[2][4096];
    int tid = threadIdx.x;
    int bm0 = m_ << 7, bn0 = n_ << 7;
    int lane = tid & 63, wid = tid >> 6, wm = wid >> 1, wn = wid & 1;
    int fr = lane & 15, g = lane >> 4;
    const u16* srcA0 = A + (size_t)(bm0 + (tid & 127)) * K + ((tid >> 7) << 3);
    const u16* srcA1 = srcA0 + 16;
    const u16* srcB0 = BT + (size_t)(bn0 + (tid & 127)) * K + ((tid >> 7) << 3);
    const u16* srcB1 = srcB0 + 16;
    auto STAGE = [&](int buf, int k0) {
        gld16(srcA0 + k0, &lA[buf][0] + tid * 8);
        gld16(srcA1 + k0, &lA[buf][0] + 2048 + tid * 8);
        gld16(srcB0 + k0, &lB[buf][0] + tid * 8);
        gld16(srcB1 + k0, &lB[buf][0] + 2048 + tid * 8);
    };
    f32x4 acc[4][4] = {};
    STAGE(0, 0);
    __syncthreads();
    int cur = 0;
    for (int k0 = 0; k0 < K; k0 += 32) {
        if (k0 + 32 < K) STAGE(cur ^ 1, k0 + 32);
        s16x8 af[4], bf[4];
#pragma unroll
        for (int i = 0; i < 4; ++i)
            af[i] = *(const s16x8*)&lA[cur][(g * 128 + wm * 64 + i * 16 + fr) * 8];
#pragma unroll
        for (int j = 0; j < 4; ++j)
            bf[j] = *(const s16x8*)&lB[cur][(g * 128 + wn * 64 + j * 16 + fr) * 8];
#pragma unroll
        for (int i = 0; i < 4; ++i)
#pragma unroll
            for (int j = 0; j < 4; ++j)
                acc[i][j] = mfma16(af[i], bf[j], acc[i][j]);
        __syncthreads();
        cur ^= 1;
    }
    int seg = bn0 / 768;
    const float* bp = seg == 0 ? (z ? bqd : bq) : seg == 1 ? (z ? bkd : bk) : (z ? bvd : bv);
    u16* out;
    size_t zoff;
    if (seg == 0)      { out = Qd; zoff = (size_t)z * 3 * EL; }
    else if (seg == 1) { out = Kd; zoff = (size_t)z * 3 * EL; }
    else               { out = Vd; zoff = (size_t)z * EL; }
    int nbase = bn0 - seg * 768;
    const float qs = (seg == 0) ? 0.180336880f : 1.0f;  // 0.125 * log2(e)
#pragma unroll
    for (int j = 0; j < 4; ++j) {
        int nn = nbase + wn * 64 + j * 16 + fr;
        float bvl = bp[nn];
        int hh = nn >> 6, hd = nn & 63;
#pragma unroll
        for (int i = 0; i < 4; ++i) {
#pragma unroll
            for (int r = 0; r < 4; ++r) {
                int m = bm0 + wm * 64 + i * 16 + (g << 2) + r;
                int bb = m >> 10, ss = m & 1023;
                size_t o = zoff + (((size_t)(bb * 12 + hh)) << 16) + ((size_t)ss << 6) + hd;
                out[o] = f2bf((acc[i][j][r] + bvl) * qs);
            }
        }
    }
}

// ------- fused attention v9: double-buffered K/V with prefetch ---------------
// STAGE(t+1) issues right after the barrier, BEFORE computing tile t (gemm_k
// pattern). One barrier per tile. K chunk swizzle c^=(row&7); V chunk swizzle
// c^=((row>>1)&3) (both verified bijective; R21 counters confirmed).
__global__ __launch_bounds__(256) void attn_k(const u16* __restrict__ Qx,
                                              const u16* __restrict__ Kx,
                                              const u16* __restrict__ VTx,
                                              const u16* __restrict__ Qy,
                                              const u16* __restrict__ Ky,
                                              const u16* __restrict__ VTy,
                                              u16* __restrict__ csx,
                                              u16* __restrict__ ccx,
                                              u16* __restrict__ csy,
                                              u16* __restrict__ ccy) {
    int p = blockIdx.x;
    int lg = (p & 7) * 192 + (p >> 3);       // contiguous logical ids per XCD
    int sg = lg >> 4, wi = lg & 15;          // supergroup = K/V-sharing pair
    int qt = wi & 7, sub = wi >> 3;
    int pairi = sg / 48, bh = sg % 48;
    int cfg = pairi == 0 ? (sub ? 3 : 0) : (sub ? 2 : 1);
    const u16 *Qp, *Kp, *Vp;
    u16* Op;
    if (cfg == 0)      { Qp = Qx; Kp = Kx; Vp = VTx; Op = csx; }
    else if (cfg == 1) { Qp = Qy; Kp = Ky; Vp = VTy; Op = csy; }
    else if (cfg == 2) { Qp = Qx; Kp = Ky; Vp = VTy; Op = ccx; }
    else               { Qp = Qy; Kp = Kx; Vp = VTx; Op = ccy; }
    const u16* Qh = Qp + ((size_t)bh << 16);
    const u16* Kh = Kp + ((size_t)bh << 16);
    const u16* Vh = Vp + ((size_t)bh << 16);
    int b = bh / 12, h = bh % 12;
    int tid = threadIdx.x, lane = tid & 63, w = tid >> 6;
    int q0 = qt * 128 + w * 32;
    int fr = lane & 15, ko = (lane >> 4) << 3, g = lane >> 4;
    bool glo = lane < 32;
    int srcA = fr + ((lane & 16) << 1);
    int srcB = srcA + 16;

    __shared__ u16 kls[8192];   // 2 buf x 2 x (32 keys x 64 d), chunk-swizzled
    __shared__ u16 vls[8192];   // 2 buf x 2 x (64 d x 32 keys), chunk-swizzled

    s16x8 qf[2][2];
#pragma unroll
    for (int s = 0; s < 2; ++s) {
        const u16* qp = Qh + (size_t)(q0 + s * 16 + fr) * 64 + ko;
        qf[s][0] = *(const s16x8*)qp;
        qf[s][1] = *(const s16x8*)(qp + 32);
    }

    f32x4 acc[2][4] = {};
    float lsum[2] = {0.f, 0.f};
    f32x4 zz = {0.f, 0.f, 0.f, 0.f};

    int krow = tid >> 3, kpc = tid & 7;
    int kgc = kpc ^ (krow & 7);              // K source-chunk swizzle
    int vdr = tid >> 2, vpv = tid & 3;
    int vgc = vpv ^ ((vdr >> 1) & 3);        // V source-chunk swizzle
    int cK0 = ((fr << 3) + (g ^ (fr & 7))) << 3;
    int cK1 = ((fr << 3) + ((g + 4) ^ (fr & 7))) << 3;
    int cK2 = (((fr + 16) << 3) + (g ^ (fr & 7))) << 3;
    int cK3 = (((fr + 16) << 3) + ((g + 4) ^ (fr & 7))) << 3;
    int cVg = (g ^ ((fr >> 1) & 3)) << 3;    // V read-chunk

    auto STAGE = [&](int buf, int kb) {
        int lb = buf * 4096 + tid * 8;
        gld16(Kh + (size_t)(kb + krow) * 64 + kgc * 8, &kls[lb]);
        gld16(Kh + (size_t)(kb + 32 + krow) * 64 + kgc * 8, &kls[lb + 2048]);
        gld16(Vh + (size_t)vdr * 1024 + kb + vgc * 8, &vls[lb]);
        gld16(Vh + (size_t)vdr * 1024 + kb + 32 + vgc * 8, &vls[lb + 2048]);
    };

    auto HALF = [&](int base) {
        s16x8 Kf0 = *(const s16x8*)&kls[base + cK0];
        s16x8 Kf1 = *(const s16x8*)&kls[base + cK1];
        s16x8 Kf2 = *(const s16x8*)&kls[base + cK2];
        s16x8 Kf3 = *(const s16x8*)&kls[base + cK3];
        s16x8 Vf[4];
#pragma unroll
        for (int t4 = 0; t4 < 4; ++t4)
            Vf[t4] = *(const s16x8*)&vls[base + ((t4 * 16 + fr) << 5) + cVg];
        s16x8 pa[2];
#pragma unroll
        for (int s = 0; s < 2; ++s) {
            __builtin_amdgcn_s_setprio(1);
            f32x4 t0 = mfma16(Kf0, qf[s][0], zz);
            t0 = mfma16(Kf1, qf[s][1], t0);
            f32x4 t1 = mfma16(Kf2, qf[s][0], zz);
            t1 = mfma16(Kf3, qf[s][1], t1);
            __builtin_amdgcn_s_setprio(0);
            float p00 = EXP2(t0[0]), p01 = EXP2(t0[1]);
            float p02 = EXP2(t0[2]), p03 = EXP2(t0[3]);
            float p10 = EXP2(t1[0]), p11 = EXP2(t1[1]);
            float p12 = EXP2(t1[2]), p13 = EXP2(t1[3]);
            lsum[s] += (p00 + p01 + p02 + p03) + (p10 + p11 + p12 + p13);
            unsigned w0, w1, w2, w3;
            asm("v_cvt_pk_bf16_f32 %0, %1, %2" : "=v"(w0) : "v"(p00), "v"(p01));
            asm("v_cvt_pk_bf16_f32 %0, %1, %2" : "=v"(w1) : "v"(p02), "v"(p03));
            asm("v_cvt_pk_bf16_f32 %0, %1, %2" : "=v"(w2) : "v"(p10), "v"(p11));
            asm("v_cvt_pk_bf16_f32 %0, %1, %2" : "=v"(w3) : "v"(p12), "v"(p13));
            int e0 = __shfl((int)w0, srcA), e1 = __shfl((int)w1, srcA);
            int e2 = __shfl((int)w0, srcB), e3 = __shfl((int)w1, srcB);
            int f0 = __shfl((int)w2, srcA), f1 = __shfl((int)w3, srcA);
            int f2 = __shfl((int)w2, srcB), f3 = __shfl((int)w3, srcB);
            int4 wd;
            wd.x = glo ? e0 : f0;
            wd.y = glo ? e1 : f1;
            wd.z = glo ? e2 : f2;
            wd.w = glo ? e3 : f3;
            pa[s] = __builtin_bit_cast(s16x8, wd);
        }
        __builtin_amdgcn_s_setprio(1);
#pragma unroll
        for (int t4 = 0; t4 < 4; ++t4) {
            acc[0][t4] = mfma16(pa[0], Vf[t4], acc[0][t4]);
            acc[1][t4] = mfma16(pa[1], Vf[t4], acc[1][t4]);
        }
        __builtin_amdgcn_s_setprio(0);
    };

    STAGE(0, 0);
    int cur = 0;
    for (int kb = 0; kb < 1024; kb += 64) {
        __syncthreads();   // buffer `cur` staged; all reads of cur^1 finished
        if (kb + 64 < 1024) STAGE(cur ^ 1, kb + 64);  // fly during compute
        HALF(cur * 4096);
        HALF(cur * 4096 + 2048);
        cur ^= 1;
    }

    float invv[2][4];
#pragma unroll
    for (int s = 0; s < 2; ++s) {
        float l = lsum[s];
        l += __shfl_xor(l, 16);
        l += __shfl_xor(l, 32);
        float inv = 1.0f / l;
#pragma unroll
        for (int r = 0; r < 4; ++r)
            invv[s][r] = __shfl(inv, ((lane >> 4) << 2) + r);
    }
#pragma unroll
    for (int s = 0; s < 2; ++s) {
        u16* ob = Op + (size_t)(b * 1024 + q0 + s * 16 + ((lane >> 4) << 2)) * 768 + h * 64 + fr;
#pragma unroll
        for (int t4 = 0; t4 < 4; ++t4)
#pragma unroll
            for (int r = 0; r < 4; ++r)
                ob[(size_t)r * 768 + t4 * 16] = f2bf(acc[s][t4][r] * invv[s][r]);
    }
}

// -----------------------------------------------------------------------------
extern "C" void kernel_launch(void* const* d_in, const int* in_sizes, int n_in,
                              void* d_out, int out_size, void* d_ws, size_t ws_size,
                              hipStream_t stream) {
    (void)in_sizes; (void)n_in; (void)out_size; (void)ws_size;
    const float* X    = (const float*)d_in[0];
    const float* Y    = (const float*)d_in[1];
    const float* l1xg = (const float*)d_in[2];
    const float* l1xb = (const float*)d_in[3];
    const float* l1yg = (const float*)d_in[4];
    const float* l1yb = (const float*)d_in[5];
    const float* Wq   = (const float*)d_in[6];
    const float* bq   = (const float*)d_in[7];
    const float* Wk   = (const float*)d_in[8];
    const float* bk   = (const float*)d_in[9];
    const float* Wv   = (const float*)d_in[10];
    const float* bv   = (const float*)d_in[11];
    const float* Wo   = (const float*)d_in[12];
    const float* bo   = (const float*)d_in[13];
    const float* Wqd  = (const float*)d_in[14];
    const float* bqd  = (const float*)d_in[15];
    const float* Wkd  = (const float*)d_in[16];
    const float* bkd  = (const float*)d_in[17];
    const float* Wvd  = (const float*)d_in[18];
    const float* bvd  = (const float*)d_in[19];
    const float* Wod  = (const float*)d_in[20];
    const float* bod  = (const float*)d_in[21];
    const float* w11  = (const float*)d_in[22];
    const float* w12  = (const float*)d_in[23];
    const float* w21  = (const float*)d_in[24];
    const float* w22  = (const float*)d_in[25];
    const float* l2xg = (const float*)d_in[26];
    const float* l2xb = (const float*)d_in[27];
    const float* l2yg = (const float*)d_in[28];
    const float* l2yb = (const float*)d_in[29];
    const float* W1   = (const float*)d_in[30];
    const float* b1   = (const float*)d_in[31];
    const float* W2   = (const float*)d_in[32];
    const float* b2   = (const float*)d_in[33];
    const float* W1d  = (const float*)d_in[34];
    const float* b1d  = (const float*)d_in[35];
    const float* W2d  = (const float*)d_in[36];
    const float* b2d  = (const float*)d_in[37];

    u16* ws = (u16*)d_ws;
    u16* qkvT = ws;
    u16* WoT  = qkvT + 6 * DDE;
    u16* W1T  = WoT + 2 * DDE;
    u16* W2T  = W1T + 2 * DFE;
    u16* xn   = W2T + 2 * DFE;   // 2E: xn,yn (also LN2 outs later)
    u16* Qx   = xn + 2 * EL;     // 6E: Qx,Kx,VTx,Qy,Ky,VTy ; h aliases (8E)
    u16* cs   = Qx + 6 * EL;     // 4E: csx,csy,ccx,ccy (also Vrow scratch)
    u16* x1   = cs + 4 * EL;     // 2E bf16: x1,y1
    u16* Kx = Qx + EL;
    u16* VTx = Qx + 2 * EL;
    u16* h = Qx;                 // MLP hidden: x at h, y at h+4E
    u16* y1 = x1 + EL;
    u16* Vrow = cs;              // V row-major scratch (2E), dead before attn writes cs

    float* out_x = (float*)d_out;

    // Monolithic MLP2 (KS=1): measured faster than split-K(4)+combine at the
    // current balance (107 vs ~112 us) and saves ~100MB of parts traffic.
    const int KS = 1;

    dim3 tb(256);
    transpose8_k<<<dim3(12, 12, 8), tb, 0, stream>>>(Wq, Wk, Wv, Wqd, Wkd, Wvd, Wo, Wod, qkvT);
    transpose2_k<<<dim3(48, 12, 2), tb, 0, stream>>>(W1, W1d, W1T, DFE, 768, 3072);
    transpose2_k<<<dim3(12, 48, 2), tb, 0, stream>>>(W2, W2d, W2T, DFE, 3072, 768);
    ln_k<<<dim3(4096, 2), tb, 0, stream>>>(X, Y, l1xg, l1xb, l1yg, l1yb, xn);
    gemm_qkv_k<<<1152, tb, 0, stream>>>(xn, qkvT, bq, bk, bv, bqd, bkd, bvd,
                                        Qx, Kx, Vrow);
    vtrans_k<<<dim3(16, 48, 2), tb, 0, stream>>>(Vrow, VTx);
    attn_k<<<4 * 48 * 8, tb, 0, stream>>>(Qx, Kx, VTx, Qx + 3 * EL, Qx + 4 * EL, Qx + 5 * EL,
                                          cs, cs + 2 * EL, cs + EL, cs + 3 * EL);
    int n8 = (int)(EL / 8);
    blend_k<<<dim3(1536, 1, 2), tb, 0, stream>>>(cs, cs + 2 * EL, w11, w12, w21, w22, n8);
    gemm_k<EPI_WO><<<384, tb, 0, stream>>>(
        cs, EL, WoT, DDE, bo, bod, X, Y, w11, w12, w21, w22, x1, EL,
        4096, 768, 768, 6, 1);
    lnb_k<<<dim3(4096, 2), tb, 0, stream>>>(x1, y1, l2xg, l2xb, l2yg, l2yb, xn);
    gemm_k<EPI_GELU><<<1536, tb, 0, stream>>>(
        xn, EL, W1T, DFE, b1, b1d, nullptr, nullptr, nullptr, nullptr, nullptr, nullptr,
        h, 4 * EL, 4096, 3072, 768, 24, 1);
    // MLP2 monolithic: resid bf16 x1/y1, +bias, out f32 d_out
    gemm_k<EPI_MLP2><<<384 * KS, tb, 0, stream>>>(
        h, 4 * EL, W2T, DFE, b2, b2d, x1, y1,
        nullptr, nullptr, nullptr, nullptr,
        out_x, EL, 4096, 768, 3072, 6, KS);
}